// Round 4
// baseline (449.032 us; speedup 1.0000x reference)
//
#include <hip/hip_runtime.h>

#define B_ 16
#define N_ 16384
#define K_ 16

// ---- workspace layout (float offsets) ----
enum : int {
  WS_LAT  = 0,      // 32 x 128 latent (f32, atomicMax-as-uint, relu>=0)
  WS_W1F  = 31840,  // 64 x 3  bn-folded (fp32)
  WS_B1F  = 32032,  // 64
  // split-f16 B-fragment tables (MFMA layout), built by prep:
  WS_WB2H = 32096,  // 8192 f16 (4096 floats): layer2 B hi frags [nt*2+kt][lane][8]
  WS_WB2L = 36192,  // 8192 f16
  WS_B2F  = 40288,  // 128 fp32 folded bias
  WS_WB3H = 40416,  // 32768 f16 (16384 floats): layer3 B hi frags [nt*4+kt][lane][8]
  WS_B3F  = 56800,  // 128 fp32 folded bias
  WS_WB3L = 56928,  // 32768 f16 (16384 floats)
  WS_END  = 73312
};

enum : int { OUT_DEF=0, OUT_SRCKP=786432, OUT_TGTKP=787200 };

typedef _Float16 f16x8 __attribute__((ext_vector_type(8)));
typedef _Float16 f16x2 __attribute__((ext_vector_type(2)));
typedef float    f32x4 __attribute__((ext_vector_type(4)));

__device__ __forceinline__ float dist2rn(float px,float py,float pz,float sx,float sy,float sz){
  float dx=__fsub_rn(px,sx), dy=__fsub_rn(py,sy), dz=__fsub_rn(pz,sz);
  return __fadd_rn(__fadd_rn(__fmul_rn(dx,dx),__fmul_rn(dy,dy)),__fmul_rn(dz,dz));
}

// ---------------- prep: fold BN into encoder weights + split-f16 frags --------
struct EncW {
  const float *w1,*b1,*g1,*be1,*m1,*v1;
  const float *w2,*b2,*g2,*be2,*m2,*v2;
  const float *w3,*b3,*g3,*be3,*m3,*v3;
};

__device__ __forceinline__ float bn_scale(const float* g, const float* v, int ch){
  return g[ch] * (1.0f / sqrtf(v[ch] + 1e-5f));
}

__global__ void prep_kernel(EncW a, float* ws){
  const int stride = gridDim.x*blockDim.x;
  const int tid = blockIdx.x*blockDim.x + threadIdx.x;
  for (int i=tid;i<4096;i+=stride)            // zero latent (atomicMax target)
    ws[WS_LAT+i] = 0.0f;
  for (int i=tid;i<192;i+=stride){            // W1F (fp32: layer1 stays on VALU)
    int o=i/3;
    ws[WS_W1F+i] = a.w1[i] * bn_scale(a.g1,a.v1,o);
  }
  for (int i=tid;i<64;i+=stride){             // B1F
    float s = bn_scale(a.g1,a.v1,i);
    ws[WS_B1F+i] = (a.b1[i] - a.m1[i])*s + a.be1[i];
  }
  // layer2 B-frags, split f16 hi/lo. frag layout: lane l of MFMA B operand holds
  // B[k = kt*32 + (l>>4)*8 + j][col = nt*16 + (l&15)], j=0..7 contiguous.
  for (int i=tid;i<8192;i+=stride){
    int j = i & 7, frag = i >> 3;
    int l = frag & 63, nk = frag >> 6;        // nk = nt*2 + kt
    int kt = nk & 1, nt = nk >> 1;
    int c = kt*32 + ((l>>4)<<3) + j;          // 0..63 in-channel (K)
    int o = nt*16 + (l&15);                   // 0..127 out-channel (N)
    float v = a.w2[o*64+c] * bn_scale(a.g2,a.v2,o);
    _Float16 h = (_Float16)v;
    ((_Float16*)(ws+WS_WB2H))[i] = h;
    ((_Float16*)(ws+WS_WB2L))[i] = (_Float16)(v - (float)h);
  }
  for (int i=tid;i<128;i+=stride){
    float s = bn_scale(a.g2,a.v2,i);
    ws[WS_B2F+i] = (a.b2[i] - a.m2[i])*s + a.be2[i];
  }
  // layer3 B-frags, split f16 hi/lo
  for (int i=tid;i<32768;i+=stride){
    int j = i & 7, frag = i >> 3;
    int l = frag & 63, nk = frag >> 6;        // nk = nt*4 + kt
    int kt = nk & 3, nt = nk >> 2;
    int c = kt*32 + ((l>>4)<<3) + j;          // 0..127 in-channel (K)
    int o = nt*16 + (l&15);                   // 0..127 out-channel (N)
    float v = a.w3[o*128+c] * bn_scale(a.g3,a.v3,o);
    _Float16 h = (_Float16)v;
    ((_Float16*)(ws+WS_WB3H))[i] = h;
    ((_Float16*)(ws+WS_WB3L))[i] = (_Float16)(v - (float)h);
  }
  for (int i=tid;i<128;i+=stride){
    float s = bn_scale(a.g3,a.v3,i);
    ws[WS_B3F+i] = (a.b3[i] - a.m3[i])*s + a.be3[i];
  }
}

// ---------------- encoder v12: 64-pt tile, 256 thr, 32KB LDS (unchanged) ------
__global__ __launch_bounds__(256, 4) void encode_kernel(const float* __restrict__ src,
                                                        const float* __restrict__ tgt,
                                                        const float* __restrict__ ws,
                                                        float* __restrict__ lat){
  const int cloud = blockIdx.y;
  const int tile  = blockIdx.x;              // 256 tiles/cloud, 64 pts each
  const int t = threadIdx.x;
  const int lane = t & 63;
  const int wn = __builtin_amdgcn_readfirstlane(t >> 6);   // 0..3 : cols 32*wn..+31
  const int lr = lane & 15;                  // row/col within 16x16 tile
  const int lg = lane >> 4;                  // k-group

  __shared__ alignas(16) _Float16 A[16384];  // 32KB
  _Float16* AH1 = A;                         // [64][64]  layer2 input hi
  _Float16* AL1 = A + 4096;                  //           layer2 input lo
  _Float16* AH2 = A;                         // [64][128] layer3 input hi (overlay)
  _Float16* AL2 = A + 8192;                  //           layer3 input lo

  const float* base = ((cloud < B_) ? (src + (size_t)cloud*N_*3)
                                    : (tgt + (size_t)(cloud-B_)*N_*3))
                      + (size_t)tile*64*3;

  // ---- layer 1 (3->64), fp32 VALU: thread t -> point t>>2, channels (t&3)*16..+15
  {
    const int pt = t >> 2, q = t & 3;        // pt 0..63
    const float x = base[pt*3+0], y = base[pt*3+1], z = base[pt*3+2];
    const float* w1 = ws + WS_W1F;
    const float* b1 = ws + WS_B1F;
    const int swz = (pt & 7) << 3;
    #pragma unroll
    for (int cc = 0; cc < 16; cc += 2){
      const int o = q*16 + cc;
      float v0 = fmaf(w1[o*3+2], z, fmaf(w1[o*3+1], y, w1[o*3+0]*x)) + b1[o];
      float v1 = fmaf(w1[o*3+5], z, fmaf(w1[o*3+4], y, w1[o*3+3]*x)) + b1[o+1];
      v0 = fmaxf(v0, 0.0f); v1 = fmaxf(v1, 0.0f);
      f16x2 h, l;
      h[0] = (_Float16)v0;              h[1] = (_Float16)v1;
      l[0] = (_Float16)(v0 - (float)h[0]); l[1] = (_Float16)(v1 - (float)h[1]);
      const int idx = (pt*64 + o) ^ swz;
      *(f16x2*)&AH1[idx] = h;
      *(f16x2*)&AL1[idx] = l;
    }
  }
  __syncthreads();

  // ---- layer 2 (64->128): M64 K64 N128, 3-term split MFMA
  f32x4 acc2[4][2];
  #pragma unroll
  for (int m=0;m<4;m++){
    #pragma unroll
    for (int n=0;n<2;n++) acc2[m][n] = (f32x4){0.f,0.f,0.f,0.f};
  }
  {
    const _Float16* wb2h = (const _Float16*)(ws + WS_WB2H);
    const _Float16* wb2l = (const _Float16*)(ws + WS_WB2L);
    const int swz = (lr & 7) << 3;
    #pragma unroll
    for (int kt=0; kt<2; kt++){
      f16x8 bh[2], bl[2];
      #pragma unroll
      for (int n=0;n<2;n++){
        const int fi = (((wn*2+n)*2 + kt)*64 + lane)*8;
        bh[n] = *(const f16x8*)(wb2h + fi);
        bl[n] = *(const f16x8*)(wb2l + fi);
      }
      #pragma unroll
      for (int m=0;m<4;m++){
        const int row = m*16 + lr;           // 0..63
        const int idx = (row*64 + kt*32 + lg*8) ^ swz;
        const f16x8 ah = *(const f16x8*)&AH1[idx];
        const f16x8 al = *(const f16x8*)&AL1[idx];
        #pragma unroll
        for (int n=0;n<2;n++){
          acc2[m][n] = __builtin_amdgcn_mfma_f32_16x16x32_f16(ah, bh[n], acc2[m][n], 0,0,0);
          acc2[m][n] = __builtin_amdgcn_mfma_f32_16x16x32_f16(ah, bl[n], acc2[m][n], 0,0,0);
          acc2[m][n] = __builtin_amdgcn_mfma_f32_16x16x32_f16(al, bh[n], acc2[m][n], 0,0,0);
        }
      }
    }
  }
  __syncthreads();   // all h1 reads complete before overlay write

  // h2 = relu(acc2 + b2): split hi/lo -> LDS
  {
    const float* b2 = ws + WS_B2F;
    #pragma unroll
    for (int n=0;n<2;n++){
      const int ch = wn*32 + n*16 + lr;
      const float b = b2[ch];
      #pragma unroll
      for (int m=0;m<4;m++){
        #pragma unroll
        for (int r=0;r<4;r++){
          const int row = m*16 + lg*4 + r;   // 0..63
          const float v = fmaxf(acc2[m][n][r] + b, 0.0f);
          const _Float16 hi = (_Float16)v;
          const _Float16 lo = (_Float16)(v - (float)hi);
          const int idx = (row*128 + ch) ^ ((row & 7) << 3);
          AH2[idx] = hi;
          AL2[idx] = lo;
        }
      }
    }
  }
  __syncthreads();

  // ---- layer 3 (128->128): M64 K128 N128, 3-term split MFMA
  f32x4 acc3[4][2];
  #pragma unroll
  for (int m=0;m<4;m++){
    #pragma unroll
    for (int n=0;n<2;n++) acc3[m][n] = (f32x4){0.f,0.f,0.f,0.f};
  }
  {
    const _Float16* wb3h = (const _Float16*)(ws + WS_WB3H);
    const _Float16* wb3l = (const _Float16*)(ws + WS_WB3L);
    const int swz = (lr & 7) << 3;
    #pragma unroll
    for (int kt=0; kt<4; kt++){
      f16x8 bh[2], bl[2];
      #pragma unroll
      for (int n=0;n<2;n++){
        const int fi = (((wn*2+n)*4 + kt)*64 + lane)*8;
        bh[n] = *(const f16x8*)(wb3h + fi);
        bl[n] = *(const f16x8*)(wb3l + fi);
      }
      #pragma unroll
      for (int m=0;m<4;m++){
        const int row = m*16 + lr;           // 0..63
        const int idx = (row*128 + kt*32 + lg*8) ^ swz;
        const f16x8 ah = *(const f16x8*)&AH2[idx];
        const f16x8 al = *(const f16x8*)&AL2[idx];
        #pragma unroll
        for (int n=0;n<2;n++){
          acc3[m][n] = __builtin_amdgcn_mfma_f32_16x16x32_f16(ah, bh[n], acc3[m][n], 0,0,0);
          acc3[m][n] = __builtin_amdgcn_mfma_f32_16x16x32_f16(ah, bl[n], acc3[m][n], 0,0,0);
          acc3[m][n] = __builtin_amdgcn_mfma_f32_16x16x32_f16(al, bh[n], acc3[m][n], 0,0,0);
        }
      }
    }
  }

  // epilogue: bias+relu, max over this wave's 64 rows, cross-group shfl, atomic
  {
    const float* b3 = ws + WS_B3F;
    #pragma unroll
    for (int n=0;n<2;n++){
      const int ch = wn*32 + n*16 + lr;
      const float b = b3[ch];
      float x = 0.0f;                        // relu floor
      #pragma unroll
      for (int m=0;m<4;m++){
        #pragma unroll
        for (int r=0;r<4;r++)
          x = fmaxf(x, acc3[m][n][r] + b);
      }
      x = fmaxf(x, __shfl_xor(x, 16, 64));
      x = fmaxf(x, __shfl_xor(x, 32, 64));
      if (lane < 16)
        atomicMax((unsigned*)(lat + cloud*128 + ch), __float_as_uint(x));
    }
  }
}

// ---------------- tail: minmax + kpMLP + FPS(src,tgt) + cage + deform ---------
// One block per cloud PAIR (b, b+16). All intermediates (keypoints, pmin/pmax,
// cage corners) stay in LDS; collapses 4 serial kernel launches into 1.
// Every arithmetic chain copied verbatim from the prior passing kernels.
__device__ __forceinline__ void fps_round_t(int r, int t, int wv,
                                            float bv, int bi, float bx, float by, float bz,
                                            float (*cv)[16], int (*ci)[16],
                                            float (*cx)[16], float (*cy)[16], float (*cz)[16],
                                            float* sel_buf, float* out, size_t out_base,
                                            float& s0, float& s1, float& s2){
  float v = bv; int i = bi;
  #pragma unroll
  for (int m=1;m<64;m<<=1){
    float v2=__shfl_xor(v,m,64); int i2=__shfl_xor(i,m,64);
    if (v2 > v || (v2 == v && i2 < i)){ v=v2; i=i2; }
  }
  const int p = r & 1;
  if ((i >> 4) == t){ cv[p][wv]=v; ci[p][wv]=i; cx[p][wv]=bx; cy[p][wv]=by; cz[p][wv]=bz; }
  __syncthreads();
  float wvv = cv[p][0]; int wi = ci[p][0]; int slot = 0;
  #pragma unroll
  for (int e=1;e<16;e++){
    float v2=cv[p][e]; int i2=ci[p][e];
    if (v2 > wvv || (v2 == wvv && i2 < wi)){ wvv=v2; wi=i2; slot=e; }
  }
  s0 = cx[p][slot]; s1 = cy[p][slot]; s2 = cz[p][slot];
  if (t == 0){
    sel_buf[r*3]=s0; sel_buf[r*3+1]=s1; sel_buf[r*3+2]=s2;
    out[out_base + r*3]=s0; out[out_base + r*3+1]=s1; out[out_base + r*3+2]=s2;
  }
}

__global__ __launch_bounds__(1024) void tail_kernel(const float* __restrict__ src,
                                                    const float* __restrict__ tgt,
                                                    const float* __restrict__ kw1,
                                                    const float* __restrict__ kb1,
                                                    const float* __restrict__ kw2,
                                                    const float* __restrict__ kb2,
                                                    const float* __restrict__ cw1,
                                                    const float* __restrict__ cb1,
                                                    const float* __restrict__ cw2,
                                                    const float* __restrict__ cb2,
                                                    const float* __restrict__ ws,
                                                    float* __restrict__ out){
  const int b = blockIdx.x;                  // pair id 0..15
  const int t = threadIdx.x;
  const int wv = t >> 6;
  const int lane = t & 63;

  __shared__ float kpl[48];
  __shared__ float h[128];
  __shared__ float cv[2][16]; __shared__ int ci[2][16];
  __shared__ float cx[2][16]; __shared__ float cy[2][16]; __shared__ float cz[2][16];
  __shared__ float sel_src[48]; __shared__ float sel_tgt[48];
  __shared__ float red[96];                  // 16 waves x 6 channels
  __shared__ float pmn[3]; __shared__ float pmx[3];
  __shared__ float cf[1536];

  for (int half=0; half<2; ++half){
    const int cloud = b + half*B_;
    const float* base = (half==0) ? (src + (size_t)b*N_*3) : (tgt + (size_t)b*N_*3);

    // 16 consecutive points/thread via 12 float4 (coalesced)
    float px[16], py[16], pz[16];
    float mn0=3.4e38f,mn1=3.4e38f,mn2=3.4e38f, mx0=-3.4e38f,mx1=-3.4e38f,mx2=-3.4e38f;
    {
      const float4* b4 = (const float4*)(base + (size_t)t*48);
      #pragma unroll
      for (int q=0;q<4;q++){
        float4 va=b4[q*3], vb=b4[q*3+1], vc=b4[q*3+2];
        px[q*4  ]=va.x; py[q*4  ]=va.y; pz[q*4  ]=va.z;
        px[q*4+1]=va.w; py[q*4+1]=vb.x; pz[q*4+1]=vb.y;
        px[q*4+2]=vb.z; py[q*4+2]=vb.w; pz[q*4+2]=vc.x;
        px[q*4+3]=vc.y; py[q*4+3]=vc.z; pz[q*4+3]=vc.w;
      }
    }

    // src min/max (exact: fmin/fmax order-independent)
    if (half==0){
      #pragma unroll
      for (int k=0;k<16;k++){
        mn0=fminf(mn0,px[k]); mn1=fminf(mn1,py[k]); mn2=fminf(mn2,pz[k]);
        mx0=fmaxf(mx0,px[k]); mx1=fmaxf(mx1,py[k]); mx2=fmaxf(mx2,pz[k]);
      }
      #pragma unroll
      for (int m=1;m<64;m<<=1){
        mn0=fminf(mn0,__shfl_xor(mn0,m,64)); mx0=fmaxf(mx0,__shfl_xor(mx0,m,64));
        mn1=fminf(mn1,__shfl_xor(mn1,m,64)); mx1=fmaxf(mx1,__shfl_xor(mx1,m,64));
        mn2=fminf(mn2,__shfl_xor(mn2,m,64)); mx2=fmaxf(mx2,__shfl_xor(mx2,m,64));
      }
      if (lane==0){
        red[wv*6+0]=mn0; red[wv*6+1]=mn1; red[wv*6+2]=mn2;
        red[wv*6+3]=mx0; red[wv*6+4]=mx1; red[wv*6+5]=mx2;
      }
      __syncthreads();
      if (t==0){
        float a0=red[0],a1=red[1],a2=red[2],a3=red[3],a4=red[4],a5=red[5];
        for (int e=1;e<16;e++){
          a0=fminf(a0,red[e*6+0]); a1=fminf(a1,red[e*6+1]); a2=fminf(a2,red[e*6+2]);
          a3=fmaxf(a3,red[e*6+3]); a4=fmaxf(a4,red[e*6+4]); a5=fmaxf(a5,red[e*6+5]);
        }
        pmn[0]=a0; pmn[1]=a1; pmn[2]=a2; pmx[0]=a3; pmx[1]=a4; pmx[2]=a5;
      }
    }

    // kp-MLP: serial per-output chains (bit-identical to prior passing runs)
    const float* lat = ws + WS_LAT + cloud*128;
    __syncthreads();
    if (t < 128){
      float acc = kb1[t];
      const float* w = kw1 + t*128;
      for (int c=0;c<128;c++) acc = fmaf(lat[c], w[c], acc);
      h[t] = fmaxf(acc, 0.0f);
    }
    __syncthreads();
    if (t < 48){
      float acc = kb2[t];
      const float* w = kw2 + t*128;
      for (int c=0;c<128;c++) acc = fmaf(h[c], w[c], acc);
      kpl[t] = acc;
    }
    __syncthreads();

    // dmin over 16 keypoints, j-outer
    float mind[16];
    #pragma unroll
    for (int k=0;k<16;k++) mind[k] = 3.4028235e38f;
    for (int j=0;j<K_;j++){
      const float sx=kpl[j*3], sy=kpl[j*3+1], sz=kpl[j*3+2];
      #pragma unroll
      for (int k=0;k<16;k++)
        mind[k] = fminf(mind[k], dist2rn(px[k],py[k],pz[k], sx,sy,sz));
    }

    float* sel_buf = (half==0) ? sel_src : sel_tgt;
    const size_t out_base = (half==0) ? (size_t)(OUT_SRCKP + b*48) : (size_t)(OUT_TGTKP + b*48);

    // round 0
    float bv = -1.0f; int bi = 0; float bx=0.f, by=0.f, bz=0.f;
    #pragma unroll
    for (int k=0;k<16;k++){
      if (mind[k] > bv){ bv=mind[k]; bi=t*16+k; bx=px[k]; by=py[k]; bz=pz[k]; }
    }
    float s0, s1, s2;
    fps_round_t(0, t, wv, bv, bi, bx, by, bz, cv, ci, cx, cy, cz, sel_buf, out, out_base, s0, s1, s2);

    // round 1: REPLACE (matches reference)
    bv = -1.0f; bi = 0;
    #pragma unroll
    for (int k=0;k<16;k++){
      float d = dist2rn(px[k],py[k],pz[k], s0,s1,s2);
      mind[k] = d;
      if (d > bv){ bv=d; bi=t*16+k; bx=px[k]; by=py[k]; bz=pz[k]; }
    }
    fps_round_t(1, t, wv, bv, bi, bx, by, bz, cv, ci, cx, cy, cz, sel_buf, out, out_base, s0, s1, s2);

    // rounds 2..15
    for (int r=2; r<K_; ++r){
      bv = -1.0f; bi = 0;
      #pragma unroll
      for (int k=0;k<16;k++){
        float d = dist2rn(px[k],py[k],pz[k], s0,s1,s2);
        float m = fminf(mind[k], d);
        mind[k] = m;
        if (m > bv){ bv=m; bi=t*16+k; bx=px[k]; by=py[k]; bz=pz[k]; }
      }
      fps_round_t(r, t, wv, bv, bi, bx, by, bz, cv, ci, cx, cy, cz, sel_buf, out, out_base, s0, s1, s2);
    }
    __syncthreads();   // sel_buf writes visible; safe to overwrite kpl/h next half
  }

  // ---- cage MLP (chains identical to cage_mlp_kernel) ----
  __shared__ float diff[48];
  if (t<48) diff[t] = __fsub_rn(sel_tgt[t], sel_src[t]);
  __syncthreads();
  if (t<128){
    const float* w = cw1 + t*48;
    float acc = cb1[t];
    for (int j=0;j<48;j++) acc = fmaf(diff[j], w[j], acc);
    h[t] = fmaxf(acc, 0.0f);
  }
  __syncthreads();
  for (int o = t; o < 1536; o += 1024){
    const float* w = cw2 + o*128;
    float acc = cb2[o];
    for (int c=0;c<128;c++) acc = fmaf(h[c], w[c], acc);
    int flat = o/3, coord = o - flat*3;
    int u = flat>>6, v=(flat>>3)&7, z=flat&7;
    int g = (coord==0)?u:((coord==1)?v:z);
    float gv = (g==7)?1.0f:(float)g*(1.0f/7.0f);
    cf[o] = gv + acc;
  }
  __syncthreads();

  // ---- trilinear deform (per-point chain identical to deform_kernel) ----
  const float q0n=pmn[0], q1n=pmn[1], q2n=pmn[2];
  const float q0x=pmx[0], q1x=pmx[1], q2x=pmx[2];
  const float* sbase = src + (size_t)b*N_*3;
  float* obase = out + OUT_DEF + (size_t)b*N_*3;
  for (int k=0;k<16;k++){
    const int n = t + k*1024;
    const float* p = sbase + (size_t)n*3;
    float pt[3]; int id[3]; float w[3];
    #pragma unroll
    for (int c=0;c<3;c++){
      float pv = p[c];
      float mnv = (c==0)?q0n:((c==1)?q1n:q2n);
      float mxv = (c==0)?q0x:((c==1)?q1x:q2x);
      float denom = __fadd_rn(__fsub_rn(mxv, mnv), 1e-6f);
      float tc = __fmul_rn(__fdiv_rn(__fsub_rn(pv, mnv), denom), 7.0f);
      int ic = (int)tc; ic = min(max(ic,0),6);
      pt[c]=pv; id[c]=ic; w[c]=__fsub_rn(tc, (float)ic);
    }
    const int flat = (id[0]<<6) + (id[1]<<3) + id[2];
    const float* c000 = cf + flat*3;
    const float wx=w[0], wy=w[1], wz=w[2];
    const float ux=__fsub_rn(1.0f,wx), uy=__fsub_rn(1.0f,wy), uz=__fsub_rn(1.0f,wz);
    const float w000=__fmul_rn(__fmul_rn(ux,uy),uz);
    const float w100=__fmul_rn(__fmul_rn(wx,uy),uz);
    const float w010=__fmul_rn(__fmul_rn(ux,wy),uz);
    const float w110=__fmul_rn(__fmul_rn(wx,wy),uz);
    const float w001=__fmul_rn(__fmul_rn(ux,uy),wz);
    const float w101=__fmul_rn(__fmul_rn(wx,uy),wz);
    const float w011=__fmul_rn(__fmul_rn(ux,wy),wz);
    const float w111=__fmul_rn(__fmul_rn(wx,wy),wz);
    #pragma unroll
    for (int c=0;c<3;c++){
      float d = __fmul_rn(w000, c000[c]);
      d = __fadd_rn(d, __fmul_rn(w100, c000[192+c]));
      d = __fadd_rn(d, __fmul_rn(w010, c000[24+c]));
      d = __fadd_rn(d, __fmul_rn(w110, c000[216+c]));
      d = __fadd_rn(d, __fmul_rn(w001, c000[3+c]));
      d = __fadd_rn(d, __fmul_rn(w101, c000[195+c]));
      d = __fadd_rn(d, __fmul_rn(w011, c000[27+c]));
      d = __fadd_rn(d, __fmul_rn(w111, c000[219+c]));
      obase[(size_t)n*3 + c] = __fadd_rn(pt[c], d);
    }
  }
}

// ---------------- launch ------------------------------------------------------
extern "C" void kernel_launch(void* const* d_in, const int* in_sizes, int n_in,
                              void* d_out, int out_size, void* d_ws, size_t ws_size,
                              hipStream_t stream){
  const float* src = (const float*)d_in[0];
  const float* tgt = (const float*)d_in[1];
  float* ws = (float*)d_ws;
  float* out = (float*)d_out;

  EncW ew;
  ew.w1 =(const float*)d_in[2];  ew.b1 =(const float*)d_in[3];
  ew.g1 =(const float*)d_in[4];  ew.be1=(const float*)d_in[5];
  ew.m1 =(const float*)d_in[6];  ew.v1 =(const float*)d_in[7];
  ew.w2 =(const float*)d_in[8];  ew.b2 =(const float*)d_in[9];
  ew.g2 =(const float*)d_in[10]; ew.be2=(const float*)d_in[11];
  ew.m2 =(const float*)d_in[12]; ew.v2 =(const float*)d_in[13];
  ew.w3 =(const float*)d_in[14]; ew.b3 =(const float*)d_in[15];
  ew.g3 =(const float*)d_in[16]; ew.be3=(const float*)d_in[17];
  ew.m3 =(const float*)d_in[18]; ew.v3 =(const float*)d_in[19];

  prep_kernel<<<128, 256, 0, stream>>>(ew, ws);
  encode_kernel<<<dim3(256,32), 256, 0, stream>>>(src, tgt, ws, ws + WS_LAT);
  tail_kernel<<<16, 1024, 0, stream>>>(src, tgt,
      (const float*)d_in[20], (const float*)d_in[21],
      (const float*)d_in[22], (const float*)d_in[23],
      (const float*)d_in[24], (const float*)d_in[25],
      (const float*)d_in[26], (const float*)d_in[27], ws, out);
}

// Round 5
// 302.874 us; speedup vs baseline: 1.4826x; 1.4826x over previous
//
#include <hip/hip_runtime.h>

#define B_ 16
#define N_ 16384
#define K_ 16

// ---- workspace layout (float offsets) ----
enum : int {
  WS_LAT  = 0,      // 32 x 128 latent (f32, atomicMax-as-uint, relu>=0)
  WS_SEL  = 5632,   // 32 x 48 selected keypoints
  WS_PMIN = 7168,   // 16 x 3 (plain f32, written by fps block owning the cloud)
  WS_PMAX = 7216,   // 16 x 3
  WS_CF   = 7264,   // 16 x 512 x 3 cage corners
  WS_W1F  = 31840,  // 64 x 3  bn-folded (fp32)
  WS_B1F  = 32032,  // 64
  // split-f16 B-fragment tables (MFMA layout), built by prep:
  WS_WB2H = 32096,  // 8192 f16 (4096 floats): layer2 B hi frags [nt*2+kt][lane][8]
  WS_WB2L = 36192,  // 8192 f16
  WS_B2F  = 40288,  // 128 fp32 folded bias
  WS_WB3H = 40416,  // 32768 f16 (16384 floats): layer3 B hi frags [nt*4+kt][lane][8]
  WS_B3F  = 56800,  // 128 fp32 folded bias
  WS_WB3L = 56928,  // 32768 f16 (16384 floats)
  WS_END  = 73312
};

enum : int { OUT_DEF=0, OUT_SRCKP=786432, OUT_TGTKP=787200 };

typedef _Float16 f16x8 __attribute__((ext_vector_type(8)));
typedef _Float16 f16x2 __attribute__((ext_vector_type(2)));
typedef float    f32x4 __attribute__((ext_vector_type(4)));

__device__ __forceinline__ float dist2rn(float px,float py,float pz,float sx,float sy,float sz){
  float dx=__fsub_rn(px,sx), dy=__fsub_rn(py,sy), dz=__fsub_rn(pz,sz);
  return __fadd_rn(__fadd_rn(__fmul_rn(dx,dx),__fmul_rn(dy,dy)),__fmul_rn(dz,dz));
}

// ---------------- prep: fold BN into encoder weights + split-f16 frags --------
struct EncW {
  const float *w1,*b1,*g1,*be1,*m1,*v1;
  const float *w2,*b2,*g2,*be2,*m2,*v2;
  const float *w3,*b3,*g3,*be3,*m3,*v3;
};

__device__ __forceinline__ float bn_scale(const float* g, const float* v, int ch){
  return g[ch] * (1.0f / sqrtf(v[ch] + 1e-5f));
}

__global__ void prep_kernel(EncW a, float* ws){
  const int stride = gridDim.x*blockDim.x;
  const int tid = blockIdx.x*blockDim.x + threadIdx.x;
  for (int i=tid;i<4096;i+=stride)            // zero latent (atomicMax target)
    ws[WS_LAT+i] = 0.0f;
  for (int i=tid;i<192;i+=stride){            // W1F (fp32: layer1 stays on VALU)
    int o=i/3;
    ws[WS_W1F+i] = a.w1[i] * bn_scale(a.g1,a.v1,o);
  }
  for (int i=tid;i<64;i+=stride){             // B1F
    float s = bn_scale(a.g1,a.v1,i);
    ws[WS_B1F+i] = (a.b1[i] - a.m1[i])*s + a.be1[i];
  }
  // layer2 B-frags, split f16 hi/lo. frag layout: lane l of MFMA B operand holds
  // B[k = kt*32 + (l>>4)*8 + j][col = nt*16 + (l&15)], j=0..7 contiguous.
  for (int i=tid;i<8192;i+=stride){
    int j = i & 7, frag = i >> 3;
    int l = frag & 63, nk = frag >> 6;        // nk = nt*2 + kt
    int kt = nk & 1, nt = nk >> 1;
    int c = kt*32 + ((l>>4)<<3) + j;          // 0..63 in-channel (K)
    int o = nt*16 + (l&15);                   // 0..127 out-channel (N)
    float v = a.w2[o*64+c] * bn_scale(a.g2,a.v2,o);
    _Float16 h = (_Float16)v;
    ((_Float16*)(ws+WS_WB2H))[i] = h;
    ((_Float16*)(ws+WS_WB2L))[i] = (_Float16)(v - (float)h);
  }
  for (int i=tid;i<128;i+=stride){
    float s = bn_scale(a.g2,a.v2,i);
    ws[WS_B2F+i] = (a.b2[i] - a.m2[i])*s + a.be2[i];
  }
  // layer3 B-frags, split f16 hi/lo
  for (int i=tid;i<32768;i+=stride){
    int j = i & 7, frag = i >> 3;
    int l = frag & 63, nk = frag >> 6;        // nk = nt*4 + kt
    int kt = nk & 3, nt = nk >> 2;
    int c = kt*32 + ((l>>4)<<3) + j;          // 0..127 in-channel (K)
    int o = nt*16 + (l&15);                   // 0..127 out-channel (N)
    float v = a.w3[o*128+c] * bn_scale(a.g3,a.v3,o);
    _Float16 h = (_Float16)v;
    ((_Float16*)(ws+WS_WB3H))[i] = h;
    ((_Float16*)(ws+WS_WB3L))[i] = (_Float16)(v - (float)h);
  }
  for (int i=tid;i<128;i+=stride){
    float s = bn_scale(a.g3,a.v3,i);
    ws[WS_B3F+i] = (a.b3[i] - a.m3[i])*s + a.be3[i];
  }
}

// ---------------- encoder v12: 64-pt tile, 256 thr, 32KB LDS (unchanged) ------
__global__ __launch_bounds__(256, 4) void encode_kernel(const float* __restrict__ src,
                                                        const float* __restrict__ tgt,
                                                        const float* __restrict__ ws,
                                                        float* __restrict__ lat){
  const int cloud = blockIdx.y;
  const int tile  = blockIdx.x;              // 256 tiles/cloud, 64 pts each
  const int t = threadIdx.x;
  const int lane = t & 63;
  const int wn = __builtin_amdgcn_readfirstlane(t >> 6);   // 0..3 : cols 32*wn..+31
  const int lr = lane & 15;                  // row/col within 16x16 tile
  const int lg = lane >> 4;                  // k-group

  __shared__ alignas(16) _Float16 A[16384];  // 32KB
  _Float16* AH1 = A;                         // [64][64]  layer2 input hi
  _Float16* AL1 = A + 4096;                  //           layer2 input lo
  _Float16* AH2 = A;                         // [64][128] layer3 input hi (overlay)
  _Float16* AL2 = A + 8192;                  //           layer3 input lo

  const float* base = ((cloud < B_) ? (src + (size_t)cloud*N_*3)
                                    : (tgt + (size_t)(cloud-B_)*N_*3))
                      + (size_t)tile*64*3;

  // ---- layer 1 (3->64), fp32 VALU: thread t -> point t>>2, channels (t&3)*16..+15
  {
    const int pt = t >> 2, q = t & 3;        // pt 0..63
    const float x = base[pt*3+0], y = base[pt*3+1], z = base[pt*3+2];
    const float* w1 = ws + WS_W1F;
    const float* b1 = ws + WS_B1F;
    const int swz = (pt & 7) << 3;
    #pragma unroll
    for (int cc = 0; cc < 16; cc += 2){
      const int o = q*16 + cc;
      float v0 = fmaf(w1[o*3+2], z, fmaf(w1[o*3+1], y, w1[o*3+0]*x)) + b1[o];
      float v1 = fmaf(w1[o*3+5], z, fmaf(w1[o*3+4], y, w1[o*3+3]*x)) + b1[o+1];
      v0 = fmaxf(v0, 0.0f); v1 = fmaxf(v1, 0.0f);
      f16x2 h, l;
      h[0] = (_Float16)v0;              h[1] = (_Float16)v1;
      l[0] = (_Float16)(v0 - (float)h[0]); l[1] = (_Float16)(v1 - (float)h[1]);
      const int idx = (pt*64 + o) ^ swz;
      *(f16x2*)&AH1[idx] = h;
      *(f16x2*)&AL1[idx] = l;
    }
  }
  __syncthreads();

  // ---- layer 2 (64->128): M64 K64 N128, 3-term split MFMA
  f32x4 acc2[4][2];
  #pragma unroll
  for (int m=0;m<4;m++){
    #pragma unroll
    for (int n=0;n<2;n++) acc2[m][n] = (f32x4){0.f,0.f,0.f,0.f};
  }
  {
    const _Float16* wb2h = (const _Float16*)(ws + WS_WB2H);
    const _Float16* wb2l = (const _Float16*)(ws + WS_WB2L);
    const int swz = (lr & 7) << 3;
    #pragma unroll
    for (int kt=0; kt<2; kt++){
      f16x8 bh[2], bl[2];
      #pragma unroll
      for (int n=0;n<2;n++){
        const int fi = (((wn*2+n)*2 + kt)*64 + lane)*8;
        bh[n] = *(const f16x8*)(wb2h + fi);
        bl[n] = *(const f16x8*)(wb2l + fi);
      }
      #pragma unroll
      for (int m=0;m<4;m++){
        const int row = m*16 + lr;           // 0..63
        const int idx = (row*64 + kt*32 + lg*8) ^ swz;
        const f16x8 ah = *(const f16x8*)&AH1[idx];
        const f16x8 al = *(const f16x8*)&AL1[idx];
        #pragma unroll
        for (int n=0;n<2;n++){
          acc2[m][n] = __builtin_amdgcn_mfma_f32_16x16x32_f16(ah, bh[n], acc2[m][n], 0,0,0);
          acc2[m][n] = __builtin_amdgcn_mfma_f32_16x16x32_f16(ah, bl[n], acc2[m][n], 0,0,0);
          acc2[m][n] = __builtin_amdgcn_mfma_f32_16x16x32_f16(al, bh[n], acc2[m][n], 0,0,0);
        }
      }
    }
  }
  __syncthreads();   // all h1 reads complete before overlay write

  // h2 = relu(acc2 + b2): split hi/lo -> LDS
  {
    const float* b2 = ws + WS_B2F;
    #pragma unroll
    for (int n=0;n<2;n++){
      const int ch = wn*32 + n*16 + lr;
      const float b = b2[ch];
      #pragma unroll
      for (int m=0;m<4;m++){
        #pragma unroll
        for (int r=0;r<4;r++){
          const int row = m*16 + lg*4 + r;   // 0..63
          const float v = fmaxf(acc2[m][n][r] + b, 0.0f);
          const _Float16 hi = (_Float16)v;
          const _Float16 lo = (_Float16)(v - (float)hi);
          const int idx = (row*128 + ch) ^ ((row & 7) << 3);
          AH2[idx] = hi;
          AL2[idx] = lo;
        }
      }
    }
  }
  __syncthreads();

  // ---- layer 3 (128->128): M64 K128 N128, 3-term split MFMA
  f32x4 acc3[4][2];
  #pragma unroll
  for (int m=0;m<4;m++){
    #pragma unroll
    for (int n=0;n<2;n++) acc3[m][n] = (f32x4){0.f,0.f,0.f,0.f};
  }
  {
    const _Float16* wb3h = (const _Float16*)(ws + WS_WB3H);
    const _Float16* wb3l = (const _Float16*)(ws + WS_WB3L);
    const int swz = (lr & 7) << 3;
    #pragma unroll
    for (int kt=0; kt<4; kt++){
      f16x8 bh[2], bl[2];
      #pragma unroll
      for (int n=0;n<2;n++){
        const int fi = (((wn*2+n)*4 + kt)*64 + lane)*8;
        bh[n] = *(const f16x8*)(wb3h + fi);
        bl[n] = *(const f16x8*)(wb3l + fi);
      }
      #pragma unroll
      for (int m=0;m<4;m++){
        const int row = m*16 + lr;           // 0..63
        const int idx = (row*128 + kt*32 + lg*8) ^ swz;
        const f16x8 ah = *(const f16x8*)&AH2[idx];
        const f16x8 al = *(const f16x8*)&AL2[idx];
        #pragma unroll
        for (int n=0;n<2;n++){
          acc3[m][n] = __builtin_amdgcn_mfma_f32_16x16x32_f16(ah, bh[n], acc3[m][n], 0,0,0);
          acc3[m][n] = __builtin_amdgcn_mfma_f32_16x16x32_f16(ah, bl[n], acc3[m][n], 0,0,0);
          acc3[m][n] = __builtin_amdgcn_mfma_f32_16x16x32_f16(al, bh[n], acc3[m][n], 0,0,0);
        }
      }
    }
  }

  // epilogue: bias+relu, max over this wave's 64 rows, cross-group shfl, atomic
  {
    const float* b3 = ws + WS_B3F;
    #pragma unroll
    for (int n=0;n<2;n++){
      const int ch = wn*32 + n*16 + lr;
      const float b = b3[ch];
      float x = 0.0f;                        // relu floor
      #pragma unroll
      for (int m=0;m<4;m++){
        #pragma unroll
        for (int r=0;r<4;r++)
          x = fmaxf(x, acc3[m][n][r] + b);
      }
      x = fmaxf(x, __shfl_xor(x, 16, 64));
      x = fmaxf(x, __shfl_xor(x, 32, 64));
      if (lane < 16)
        atomicMax((unsigned*)(lat + cloud*128 + ch), __float_as_uint(x));
    }
  }
}

// ---------------- FPS v3: 1024 thr, VGPR-128 hint, fused src minmax -----------
// R4 post-mortem: fused tail spilled (VGPR 64) -> 12.6MB scratch writes, 260us.
// v3 reverts to 32 blocks (one per cloud, src||tgt parallel) and pins 4 waves/EU
// so the 64-float point state stays in registers.
__device__ __forceinline__ void fps_round(int r, int t, int wv,
                                          float bv, int bi, float bx, float by, float bz,
                                          float (*cv)[16], int (*ci)[16],
                                          float (*cx)[16], float (*cy)[16], float (*cz)[16],
                                          float* ws, float* out, int cloud,
                                          float& s0, float& s1, float& s2){
  float v = bv; int i = bi;
  #pragma unroll
  for (int m=1;m<64;m<<=1){
    float v2=__shfl_xor(v,m,64); int i2=__shfl_xor(i,m,64);
    if (v2 > v || (v2 == v && i2 < i)){ v=v2; i=i2; }
  }
  const int p = r & 1;
  if ((i >> 4) == t){ cv[p][wv]=v; ci[p][wv]=i; cx[p][wv]=bx; cy[p][wv]=by; cz[p][wv]=bz; }
  __syncthreads();
  float wvv = cv[p][0]; int wi = ci[p][0]; int slot = 0;
  #pragma unroll
  for (int e=1;e<16;e++){
    float v2=cv[p][e]; int i2=ci[p][e];
    if (v2 > wvv || (v2 == wvv && i2 < wi)){ wvv=v2; wi=i2; slot=e; }
  }
  s0 = cx[p][slot]; s1 = cy[p][slot]; s2 = cz[p][slot];
  if (t == 0){
    float* sw = ws + WS_SEL + cloud*48 + r*3;
    sw[0]=s0; sw[1]=s1; sw[2]=s2;
    size_t o = (cloud<B_) ? (size_t)(OUT_SRCKP + cloud*48 + r*3)
                          : (size_t)(OUT_TGTKP + (cloud-B_)*48 + r*3);
    out[o]=s0; out[o+1]=s1; out[o+2]=s2;
  }
}

__global__ __launch_bounds__(1024, 4) void fps_kernel(const float* __restrict__ src,
                                                      const float* __restrict__ tgt,
                                                      const float* __restrict__ kw1,
                                                      const float* __restrict__ kb1,
                                                      const float* __restrict__ kw2,
                                                      const float* __restrict__ kb2,
                                                      float* ws, float* out){
  const int cloud = blockIdx.x; const int t = threadIdx.x;
  const int wv = t >> 6;
  const int lane = t & 63;
  const float* base = (cloud < B_) ? (src + (size_t)cloud*N_*3)
                                   : (tgt + (size_t)cloud*N_*3 - (size_t)B_*N_*3);
  __shared__ float kpl[48];
  __shared__ float h[128];
  __shared__ float cv[2][16]; __shared__ int ci[2][16];
  __shared__ float cx[2][16]; __shared__ float cy[2][16]; __shared__ float cz[2][16];
  __shared__ float red[96];

  // 16 consecutive points/thread via 12 float4 (coalesced), direct unpack
  float px[16], py[16], pz[16];
  {
    const float4* b4 = (const float4*)(base + (size_t)t*48);
    #pragma unroll
    for (int q=0;q<4;q++){
      float4 va=b4[q*3], vb=b4[q*3+1], vc=b4[q*3+2];
      px[q*4  ]=va.x; py[q*4  ]=va.y; pz[q*4  ]=va.z;
      px[q*4+1]=va.w; py[q*4+1]=vb.x; pz[q*4+1]=vb.y;
      px[q*4+2]=vb.z; py[q*4+2]=vb.w; pz[q*4+2]=vc.x;
      px[q*4+3]=vc.y; py[q*4+3]=vc.z; pz[q*4+3]=vc.w;
    }
  }

  // src cloud min/max (exact: fmin/fmax order-independent), block owns cloud
  if (cloud < B_){
    float mn0=3.4e38f,mn1=3.4e38f,mn2=3.4e38f, mx0=-3.4e38f,mx1=-3.4e38f,mx2=-3.4e38f;
    #pragma unroll
    for (int k=0;k<16;k++){
      mn0=fminf(mn0,px[k]); mn1=fminf(mn1,py[k]); mn2=fminf(mn2,pz[k]);
      mx0=fmaxf(mx0,px[k]); mx1=fmaxf(mx1,py[k]); mx2=fmaxf(mx2,pz[k]);
    }
    #pragma unroll
    for (int m=1;m<64;m<<=1){
      mn0=fminf(mn0,__shfl_xor(mn0,m,64)); mx0=fmaxf(mx0,__shfl_xor(mx0,m,64));
      mn1=fminf(mn1,__shfl_xor(mn1,m,64)); mx1=fmaxf(mx1,__shfl_xor(mx1,m,64));
      mn2=fminf(mn2,__shfl_xor(mn2,m,64)); mx2=fmaxf(mx2,__shfl_xor(mx2,m,64));
    }
    if (lane==0){
      red[wv*6+0]=mn0; red[wv*6+1]=mn1; red[wv*6+2]=mn2;
      red[wv*6+3]=mx0; red[wv*6+4]=mx1; red[wv*6+5]=mx2;
    }
    __syncthreads();
    if (t < 6){
      float v = red[t];
      for (int e=1;e<16;e++){
        float v2 = red[e*6+t];
        v = (t<3) ? fminf(v,v2) : fmaxf(v,v2);
      }
      if (t<3) ws[WS_PMIN + cloud*3 + t] = v;
      else     ws[WS_PMAX + cloud*3 + (t-3)] = v;
    }
  }
  __syncthreads();

  // kp-MLP: serial per-output chains (bit-identical to prior passing runs)
  const float* lat = ws + WS_LAT + cloud*128;
  if (t < 128){
    float acc = kb1[t];
    const float* w = kw1 + t*128;
    for (int c=0;c<128;c++) acc = fmaf(lat[c], w[c], acc);
    h[t] = fmaxf(acc, 0.0f);
  }
  __syncthreads();
  if (t < 48){
    float acc = kb2[t];
    const float* w = kw2 + t*128;
    for (int c=0;c<128;c++) acc = fmaf(h[c], w[c], acc);
    kpl[t] = acc;
  }
  __syncthreads();

  // dmin over 16 keypoints, j-outer (3 LDS broadcast reads per j)
  float mind[16];
  #pragma unroll
  for (int k=0;k<16;k++) mind[k] = 3.4028235e38f;
  for (int j=0;j<K_;j++){
    const float sx=kpl[j*3], sy=kpl[j*3+1], sz=kpl[j*3+2];
    #pragma unroll
    for (int k=0;k<16;k++)
      mind[k] = fminf(mind[k], dist2rn(px[k],py[k],pz[k], sx,sy,sz));
  }

  // round 0: argmax of keypoint-dmin
  float bv = -1.0f; int bi = 0; float bx=0.f, by=0.f, bz=0.f;
  #pragma unroll
  for (int k=0;k<16;k++){
    if (mind[k] > bv){ bv=mind[k]; bi=t*16+k; bx=px[k]; by=py[k]; bz=pz[k]; }
  }
  float s0, s1, s2;
  fps_round(0, t, wv, bv, bi, bx, by, bz, cv, ci, cx, cy, cz, ws, out, cloud, s0, s1, s2);

  // round 1: mind = dist to sel0 (REPLACE, matches reference)
  bv = -1.0f; bi = 0;
  #pragma unroll
  for (int k=0;k<16;k++){
    float d = dist2rn(px[k],py[k],pz[k], s0,s1,s2);
    mind[k] = d;
    if (d > bv){ bv=d; bi=t*16+k; bx=px[k]; by=py[k]; bz=pz[k]; }
  }
  fps_round(1, t, wv, bv, bi, bx, by, bz, cv, ci, cx, cy, cz, ws, out, cloud, s0, s1, s2);

  // rounds 2..15: mind = fmin(mind, dist to last sel)
  for (int r=2; r<K_; ++r){
    bv = -1.0f; bi = 0;
    #pragma unroll
    for (int k=0;k<16;k++){
      float d = dist2rn(px[k],py[k],pz[k], s0,s1,s2);
      float m = fminf(mind[k], d);
      mind[k] = m;
      if (m > bv){ bv=m; bi=t*16+k; bx=px[k]; by=py[k]; bz=pz[k]; }
    }
    fps_round(r, t, wv, bv, bi, bx, by, bz, cv, ci, cx, cy, cz, ws, out, cloud, s0, s1, s2);
  }
}

// ---------------- cage MLP + corner grid (64 blocks) --------------------------
__global__ void cage_mlp_kernel(const float* __restrict__ ws,
                                const float* __restrict__ cw1, const float* __restrict__ cb1,
                                const float* __restrict__ cw2, const float* __restrict__ cb2,
                                float* __restrict__ wsm){
  const int b = blockIdx.x >> 2, part = blockIdx.x & 3;
  const int t = threadIdx.x;
  __shared__ float diff[48]; __shared__ float h[128];
  if (t<48) diff[t] = __fsub_rn(ws[WS_SEL + (B_+b)*48 + t], ws[WS_SEL + b*48 + t]);
  __syncthreads();
  if (t<128){
    const float* w = cw1 + t*48;
    float acc = cb1[t];
    for (int j=0;j<48;j++) acc = fmaf(diff[j], w[j], acc);
    h[t] = fmaxf(acc, 0.0f);
  }
  __syncthreads();
  for (int o = part*384 + t; o < part*384 + 384; o += 256){
    const float* w = cw2 + o*128;
    float acc = cb2[o];
    for (int c=0;c<128;c++) acc = fmaf(h[c], w[c], acc);
    int flat = o/3, coord = o - flat*3;
    int u = flat>>6, v=(flat>>3)&7, z=flat&7;
    int g = (coord==0)?u:((coord==1)?v:z);
    float gv = (g==7)?1.0f:(float)g*(1.0f/7.0f);
    wsm[WS_CF + b*1536 + o] = gv + acc;
  }
}

// ---------------- trilinear cage deform ---------------------------------------
__global__ __launch_bounds__(256) void deform_kernel(const float* __restrict__ src,
                                                     const float* __restrict__ ws,
                                                     float* __restrict__ out){
  const int b = blockIdx.y;
  const int n = blockIdx.x*256 + threadIdx.x;
  __shared__ float cf[1536];
  for (int i=threadIdx.x;i<1536;i+=256) cf[i] = ws[WS_CF + b*1536 + i];
  __syncthreads();

  const float* p = src + ((size_t)b*N_ + n)*3;
  float pt[3]; int id[3]; float w[3];
  #pragma unroll
  for (int c=0;c<3;c++){
    float pv = p[c];
    float mn  = ws[WS_PMIN+b*3+c];
    float mxv = ws[WS_PMAX+b*3+c];
    float denom = __fadd_rn(__fsub_rn(mxv, mn), 1e-6f);
    float tc = __fmul_rn(__fdiv_rn(__fsub_rn(pv, mn), denom), 7.0f);
    int ic = (int)tc; ic = min(max(ic,0),6);
    pt[c]=pv; id[c]=ic; w[c]=__fsub_rn(tc, (float)ic);
  }
  const int flat = (id[0]<<6) + (id[1]<<3) + id[2];
  const float* c000 = cf + flat*3;
  const float wx=w[0], wy=w[1], wz=w[2];
  const float ux=__fsub_rn(1.0f,wx), uy=__fsub_rn(1.0f,wy), uz=__fsub_rn(1.0f,wz);
  const float w000=__fmul_rn(__fmul_rn(ux,uy),uz);
  const float w100=__fmul_rn(__fmul_rn(wx,uy),uz);
  const float w010=__fmul_rn(__fmul_rn(ux,wy),uz);
  const float w110=__fmul_rn(__fmul_rn(wx,wy),uz);
  const float w001=__fmul_rn(__fmul_rn(ux,uy),wz);
  const float w101=__fmul_rn(__fmul_rn(wx,uy),wz);
  const float w011=__fmul_rn(__fmul_rn(ux,wy),wz);
  const float w111=__fmul_rn(__fmul_rn(wx,wy),wz);
  #pragma unroll
  for (int c=0;c<3;c++){
    float d = __fmul_rn(w000, c000[c]);
    d = __fadd_rn(d, __fmul_rn(w100, c000[192+c]));
    d = __fadd_rn(d, __fmul_rn(w010, c000[24+c]));
    d = __fadd_rn(d, __fmul_rn(w110, c000[216+c]));
    d = __fadd_rn(d, __fmul_rn(w001, c000[3+c]));
    d = __fadd_rn(d, __fmul_rn(w101, c000[195+c]));
    d = __fadd_rn(d, __fmul_rn(w011, c000[27+c]));
    d = __fadd_rn(d, __fmul_rn(w111, c000[219+c]));
    out[((size_t)b*N_+n)*3 + c] = __fadd_rn(pt[c], d);
  }
}

// ---------------- launch ------------------------------------------------------
extern "C" void kernel_launch(void* const* d_in, const int* in_sizes, int n_in,
                              void* d_out, int out_size, void* d_ws, size_t ws_size,
                              hipStream_t stream){
  const float* src = (const float*)d_in[0];
  const float* tgt = (const float*)d_in[1];
  float* ws = (float*)d_ws;
  float* out = (float*)d_out;

  EncW ew;
  ew.w1 =(const float*)d_in[2];  ew.b1 =(const float*)d_in[3];
  ew.g1 =(const float*)d_in[4];  ew.be1=(const float*)d_in[5];
  ew.m1 =(const float*)d_in[6];  ew.v1 =(const float*)d_in[7];
  ew.w2 =(const float*)d_in[8];  ew.b2 =(const float*)d_in[9];
  ew.g2 =(const float*)d_in[10]; ew.be2=(const float*)d_in[11];
  ew.m2 =(const float*)d_in[12]; ew.v2 =(const float*)d_in[13];
  ew.w3 =(const float*)d_in[14]; ew.b3 =(const float*)d_in[15];
  ew.g3 =(const float*)d_in[16]; ew.be3=(const float*)d_in[17];
  ew.m3 =(const float*)d_in[18]; ew.v3 =(const float*)d_in[19];

  prep_kernel<<<128, 256, 0, stream>>>(ew, ws);
  encode_kernel<<<dim3(256,32), 256, 0, stream>>>(src, tgt, ws, ws + WS_LAT);
  fps_kernel<<<32, 1024, 0, stream>>>(src, tgt,
      (const float*)d_in[20], (const float*)d_in[21],
      (const float*)d_in[22], (const float*)d_in[23], ws, out);
  cage_mlp_kernel<<<64, 256, 0, stream>>>(ws,
      (const float*)d_in[24], (const float*)d_in[25],
      (const float*)d_in[26], (const float*)d_in[27], ws);
  deform_kernel<<<dim3(64,16), 256, 0, stream>>>(src, ws, out);
}

// Round 7
// 298.384 us; speedup vs baseline: 1.5049x; 1.0150x over previous
//
#include <hip/hip_runtime.h>

#define B_ 16
#define N_ 16384
#define K_ 16

// ---- workspace layout (float offsets) ----
enum : int {
  WS_LAT  = 0,      // 32 x 128 latent (f32, atomicMax-as-uint, relu>=0)
  WS_SEL  = 5632,   // 32 x 48 selected keypoints
  WS_PMIN = 7168,   // 16 x 3 (plain f32, written by fps block owning the cloud)
  WS_PMAX = 7216,   // 16 x 3
  WS_CF   = 7264,   // (unused now; cage corners computed in-block)
  WS_W1F  = 31840,  // 64 x 3  bn-folded (fp32)
  WS_B1F  = 32032,  // 64
  // split-f16 B-fragment tables (MFMA layout), built by prep:
  WS_WB2H = 32096,  // 8192 f16 (4096 floats): layer2 B hi frags [nt*2+kt][lane][8]
  WS_WB2L = 36192,  // 8192 f16
  WS_B2F  = 40288,  // 128 fp32 folded bias
  WS_WB3H = 40416,  // 32768 f16 (16384 floats): layer3 B hi frags [nt*4+kt][lane][8]
  WS_B3F  = 56800,  // 128 fp32 folded bias
  WS_WB3L = 56928,  // 32768 f16 (16384 floats)
  WS_END  = 73312
};

enum : int { OUT_DEF=0, OUT_SRCKP=786432, OUT_TGTKP=787200 };

typedef _Float16 f16x8 __attribute__((ext_vector_type(8)));
typedef _Float16 f16x2 __attribute__((ext_vector_type(2)));
typedef float    f32x4 __attribute__((ext_vector_type(4)));

__device__ __forceinline__ float dist2rn(float px,float py,float pz,float sx,float sy,float sz){
  float dx=__fsub_rn(px,sx), dy=__fsub_rn(py,sy), dz=__fsub_rn(pz,sz);
  return __fadd_rn(__fadd_rn(__fmul_rn(dx,dx),__fmul_rn(dy,dy)),__fmul_rn(dz,dz));
}

// ---------------- prep: fold BN into encoder weights + split-f16 frags --------
struct EncW {
  const float *w1,*b1,*g1,*be1,*m1,*v1;
  const float *w2,*b2,*g2,*be2,*m2,*v2;
  const float *w3,*b3,*g3,*be3,*m3,*v3;
};

__device__ __forceinline__ float bn_scale(const float* g, const float* v, int ch){
  return g[ch] * (1.0f / sqrtf(v[ch] + 1e-5f));
}

__global__ void prep_kernel(EncW a, float* ws){
  const int stride = gridDim.x*blockDim.x;
  const int tid = blockIdx.x*blockDim.x + threadIdx.x;
  for (int i=tid;i<4096;i+=stride)            // zero latent (atomicMax target)
    ws[WS_LAT+i] = 0.0f;
  for (int i=tid;i<192;i+=stride){            // W1F (fp32: layer1 stays on VALU)
    int o=i/3;
    ws[WS_W1F+i] = a.w1[i] * bn_scale(a.g1,a.v1,o);
  }
  for (int i=tid;i<64;i+=stride){             // B1F
    float s = bn_scale(a.g1,a.v1,i);
    ws[WS_B1F+i] = (a.b1[i] - a.m1[i])*s + a.be1[i];
  }
  // layer2 B-frags, split f16 hi/lo. frag layout: lane l of MFMA B operand holds
  // B[k = kt*32 + (l>>4)*8 + j][col = nt*16 + (l&15)], j=0..7 contiguous.
  for (int i=tid;i<8192;i+=stride){
    int j = i & 7, frag = i >> 3;
    int l = frag & 63, nk = frag >> 6;        // nk = nt*2 + kt
    int kt = nk & 1, nt = nk >> 1;
    int c = kt*32 + ((l>>4)<<3) + j;          // 0..63 in-channel (K)
    int o = nt*16 + (l&15);                   // 0..127 out-channel (N)
    float v = a.w2[o*64+c] * bn_scale(a.g2,a.v2,o);
    _Float16 h = (_Float16)v;
    ((_Float16*)(ws+WS_WB2H))[i] = h;
    ((_Float16*)(ws+WS_WB2L))[i] = (_Float16)(v - (float)h);
  }
  for (int i=tid;i<128;i+=stride){
    float s = bn_scale(a.g2,a.v2,i);
    ws[WS_B2F+i] = (a.b2[i] - a.m2[i])*s + a.be2[i];
  }
  // layer3 B-frags, split f16 hi/lo
  for (int i=tid;i<32768;i+=stride){
    int j = i & 7, frag = i >> 3;
    int l = frag & 63, nk = frag >> 6;        // nk = nt*4 + kt
    int kt = nk & 3, nt = nk >> 2;
    int c = kt*32 + ((l>>4)<<3) + j;          // 0..127 in-channel (K)
    int o = nt*16 + (l&15);                   // 0..127 out-channel (N)
    float v = a.w3[o*128+c] * bn_scale(a.g3,a.v3,o);
    _Float16 h = (_Float16)v;
    ((_Float16*)(ws+WS_WB3H))[i] = h;
    ((_Float16*)(ws+WS_WB3L))[i] = (_Float16)(v - (float)h);
  }
  for (int i=tid;i<128;i+=stride){
    float s = bn_scale(a.g3,a.v3,i);
    ws[WS_B3F+i] = (a.b3[i] - a.m3[i])*s + a.be3[i];
  }
}

// ---------------- encoder v13: hoisted LDS addresses + B-frag prefetch --------
// R5 post-mortem: VALUBusy 46% > MfmaUtil 31%; a large VALU slice is per-access
// XOR/mul address math. The swizzle XOR only touches f16-index bits 3-5 which
// never overlap the row/m terms, so every phase factors into one per-lane base
// pointer + compile-time byte immediates (ds offset:N). Layer2 B-frags are
// prefetched before layer1 so L2 latency hides under layer1+barrier.
// All arithmetic chains (values, per-accumulator MFMA order) bit-identical to v12.
__global__ __launch_bounds__(256, 5) void encode_kernel(const float* __restrict__ src,
                                                        const float* __restrict__ tgt,
                                                        const float* __restrict__ ws,
                                                        float* __restrict__ lat){
  const int cloud = blockIdx.y;
  const int tile  = blockIdx.x;              // 256 tiles/cloud, 64 pts each
  const int t = threadIdx.x;
  const int lane = t & 63;
  const int wn = __builtin_amdgcn_readfirstlane(t >> 6);   // 0..3 : cols 32*wn..+31
  const int lr = lane & 15;
  const int lg = lane >> 4;

  __shared__ alignas(16) _Float16 A[16384];  // 32KB
  // AH1 = A (bytes +0), AL1 = +8192B; AH2 = A (+0), AL2 = +16384B (overlay)

  const float* base = ((cloud < B_) ? (src + (size_t)cloud*N_*3)
                                    : (tgt + (size_t)(cloud-B_)*N_*3))
                      + (size_t)tile*64*3;

  // ---- prefetch layer2 B-frags (no deps; latency hides under layer1) ----
  f16x8 b2h[2][2], b2l[2][2];
  {
    const _Float16* wb2h = (const _Float16*)(ws + WS_WB2H);
    const _Float16* wb2l = (const _Float16*)(ws + WS_WB2L);
    #pragma unroll
    for (int kt=0; kt<2; kt++){
      #pragma unroll
      for (int n=0; n<2; n++){
        const int fi = (((wn*2+n)*2 + kt)*64 + lane)*8;
        b2h[kt][n] = *(const f16x8*)(wb2h + fi);
        b2l[kt][n] = *(const f16x8*)(wb2l + fi);
      }
    }
  }

  // ---- layer 1 (3->64), fp32 VALU (chain identical to v12) ----
  {
    const int pt = t >> 2, q = t & 3;        // pt 0..63
    const float x = base[pt*3+0], y = base[pt*3+1], z = base[pt*3+2];
    const float* w1 = ws + WS_W1F;
    const float* b1 = ws + WS_B1F;
    const int swz1 = (pt & 7) << 3;
    _Float16* AH1 = A;
    _Float16* AL1 = A + 4096;
    #pragma unroll
    for (int cc = 0; cc < 16; cc += 2){
      const int o = q*16 + cc;
      float v0 = fmaf(w1[o*3+2], z, fmaf(w1[o*3+1], y, w1[o*3+0]*x)) + b1[o];
      float v1 = fmaf(w1[o*3+5], z, fmaf(w1[o*3+4], y, w1[o*3+3]*x)) + b1[o+1];
      v0 = fmaxf(v0, 0.0f); v1 = fmaxf(v1, 0.0f);
      f16x2 h, l;
      h[0] = (_Float16)v0;              h[1] = (_Float16)v1;
      l[0] = (_Float16)(v0 - (float)h[0]); l[1] = (_Float16)(v1 - (float)h[1]);
      const int idx = (pt*64 + o) ^ swz1;
      *(f16x2*)&AH1[idx] = h;
      *(f16x2*)&AL1[idx] = l;
    }
  }
  __syncthreads();

  const int swz = (lr & 7) << 3;             // f16-index bits 3-5

  // ---- layer 2 (64->128): M64 K64 N128, 3-term split MFMA ----
  f32x4 acc2[4][2];
  #pragma unroll
  for (int m=0;m<4;m++){
    #pragma unroll
    for (int n=0;n<2;n++) acc2[m][n] = (f32x4){0.f,0.f,0.f,0.f};
  }
  {
    // byte addr = lr*128 + m*2048 + 2*((kt*32+lg*8)^swz); AL1 at +8192
    const char* pA0 = (const char*)A + lr*128 + ((( 0 + lg*8) ^ swz) << 1);
    const char* pA1 = (const char*)A + lr*128 + (((32 + lg*8) ^ swz) << 1);
    #pragma unroll
    for (int kt=0; kt<2; kt++){
      const char* pA = kt ? pA1 : pA0;
      #pragma unroll
      for (int m=0;m<4;m++){
        const f16x8 ah = *(const f16x8*)(pA + m*2048);
        const f16x8 al = *(const f16x8*)(pA + m*2048 + 8192);
        #pragma unroll
        for (int n=0;n<2;n++){
          acc2[m][n] = __builtin_amdgcn_mfma_f32_16x16x32_f16(ah, b2h[kt][n], acc2[m][n], 0,0,0);
          acc2[m][n] = __builtin_amdgcn_mfma_f32_16x16x32_f16(ah, b2l[kt][n], acc2[m][n], 0,0,0);
          acc2[m][n] = __builtin_amdgcn_mfma_f32_16x16x32_f16(al, b2h[kt][n], acc2[m][n], 0,0,0);
        }
      }
    }
  }
  __syncthreads();   // all h1 reads complete before overlay write

  // ---- h2 = relu(acc2 + b2): split hi/lo -> LDS (hoisted addresses) ----
  {
    #pragma unroll
    for (int n=0;n<2;n++){
      const int ch = wn*32 + n*16 + lr;
      const float b = ws[WS_B2F + ch];
      #pragma unroll
      for (int r=0;r<4;r++){
        const int mask = ((lg*4 + r) & 7) << 3;      // row&7 indep of m
        char* pW = (char*)A + ((ch ^ mask) << 1) + lg*1024 + r*256;
        #pragma unroll
        for (int m=0;m<4;m++){
          const float v = fmaxf(acc2[m][n][r] + b, 0.0f);
          const _Float16 hi = (_Float16)v;
          const _Float16 lo = (_Float16)(v - (float)hi);
          *(_Float16*)(pW + m*4096) = hi;
          *(_Float16*)(pW + m*4096 + 16384) = lo;
        }
      }
    }
  }
  __syncthreads();

  // ---- layer 3 (128->128): M64 K128 N128, 3-term split MFMA ----
  f32x4 acc3[4][2];
  #pragma unroll
  for (int m=0;m<4;m++){
    #pragma unroll
    for (int n=0;n<2;n++) acc3[m][n] = (f32x4){0.f,0.f,0.f,0.f};
  }
  {
    const _Float16* wb3h = (const _Float16*)(ws + WS_WB3H);
    const _Float16* wb3l = (const _Float16*)(ws + WS_WB3L);
    const char* pR = (const char*)A + lr*256;
    #pragma unroll
    for (int kt=0; kt<4; kt++){
      f16x8 bh[2], bl[2];
      #pragma unroll
      for (int n=0;n<2;n++){
        const int fi = (((wn*2+n)*4 + kt)*64 + lane)*8;
        bh[n] = *(const f16x8*)(wb3h + fi);
        bl[n] = *(const f16x8*)(wb3l + fi);
      }
      const int c3 = ((kt*32 + lg*8) ^ swz) << 1;    // byte offset
      #pragma unroll
      for (int m=0;m<4;m++){
        const f16x8 ah = *(const f16x8*)(pR + c3 + m*4096);
        const f16x8 al = *(const f16x8*)(pR + c3 + m*4096 + 16384);
        #pragma unroll
        for (int n=0;n<2;n++){
          acc3[m][n] = __builtin_amdgcn_mfma_f32_16x16x32_f16(ah, bh[n], acc3[m][n], 0,0,0);
          acc3[m][n] = __builtin_amdgcn_mfma_f32_16x16x32_f16(ah, bl[n], acc3[m][n], 0,0,0);
          acc3[m][n] = __builtin_amdgcn_mfma_f32_16x16x32_f16(al, bh[n], acc3[m][n], 0,0,0);
        }
      }
    }
  }

  // epilogue: bias+relu, max over this wave's 64 rows, cross-group shfl, atomic
  {
    const float* b3 = ws + WS_B3F;
    #pragma unroll
    for (int n=0;n<2;n++){
      const int ch = wn*32 + n*16 + lr;
      const float b = b3[ch];
      float x = 0.0f;                        // relu floor
      #pragma unroll
      for (int m=0;m<4;m++){
        #pragma unroll
        for (int r=0;r<4;r++)
          x = fmaxf(x, acc3[m][n][r] + b);
      }
      x = fmaxf(x, __shfl_xor(x, 16, 64));
      x = fmaxf(x, __shfl_xor(x, 32, 64));
      if (lane < 16)
        atomicMax((unsigned*)(lat + cloud*128 + ch), __float_as_uint(x));
    }
  }
}

// ---------------- FPS v3 (unchanged from R5, passing) --------------------------
__device__ __forceinline__ void fps_round(int r, int t, int wv,
                                          float bv, int bi, float bx, float by, float bz,
                                          float (*cv)[16], int (*ci)[16],
                                          float (*cx)[16], float (*cy)[16], float (*cz)[16],
                                          float* ws, float* out, int cloud,
                                          float& s0, float& s1, float& s2){
  float v = bv; int i = bi;
  #pragma unroll
  for (int m=1;m<64;m<<=1){
    float v2=__shfl_xor(v,m,64); int i2=__shfl_xor(i,m,64);
    if (v2 > v || (v2 == v && i2 < i)){ v=v2; i=i2; }
  }
  const int p = r & 1;
  if ((i >> 4) == t){ cv[p][wv]=v; ci[p][wv]=i; cx[p][wv]=bx; cy[p][wv]=by; cz[p][wv]=bz; }
  __syncthreads();
  float wvv = cv[p][0]; int wi = ci[p][0]; int slot = 0;
  #pragma unroll
  for (int e=1;e<16;e++){
    float v2=cv[p][e]; int i2=ci[p][e];
    if (v2 > wvv || (v2 == wvv && i2 < wi)){ wvv=v2; wi=i2; slot=e; }
  }
  s0 = cx[p][slot]; s1 = cy[p][slot]; s2 = cz[p][slot];
  if (t == 0){
    float* sw = ws + WS_SEL + cloud*48 + r*3;
    sw[0]=s0; sw[1]=s1; sw[2]=s2;
    size_t o = (cloud<B_) ? (size_t)(OUT_SRCKP + cloud*48 + r*3)
                          : (size_t)(OUT_TGTKP + (cloud-B_)*48 + r*3);
    out[o]=s0; out[o+1]=s1; out[o+2]=s2;
  }
}

__global__ __launch_bounds__(1024, 4) void fps_kernel(const float* __restrict__ src,
                                                      const float* __restrict__ tgt,
                                                      const float* __restrict__ kw1,
                                                      const float* __restrict__ kb1,
                                                      const float* __restrict__ kw2,
                                                      const float* __restrict__ kb2,
                                                      float* ws, float* out){
  const int cloud = blockIdx.x; const int t = threadIdx.x;
  const int wv = t >> 6;
  const int lane = t & 63;
  const float* base = (cloud < B_) ? (src + (size_t)cloud*N_*3)
                                   : (tgt + (size_t)cloud*N_*3 - (size_t)B_*N_*3);
  __shared__ float kpl[48];
  __shared__ float h[128];
  __shared__ float cv[2][16]; __shared__ int ci[2][16];
  __shared__ float cx[2][16]; __shared__ float cy[2][16]; __shared__ float cz[2][16];
  __shared__ float red[96];

  // 16 consecutive points/thread via 12 float4 (coalesced), direct unpack
  float px[16], py[16], pz[16];
  {
    const float4* b4 = (const float4*)(base + (size_t)t*48);
    #pragma unroll
    for (int q=0;q<4;q++){
      float4 va=b4[q*3], vb=b4[q*3+1], vc=b4[q*3+2];
      px[q*4  ]=va.x; py[q*4  ]=va.y; pz[q*4  ]=va.z;
      px[q*4+1]=va.w; py[q*4+1]=vb.x; pz[q*4+1]=vb.y;
      px[q*4+2]=vb.z; py[q*4+2]=vb.w; pz[q*4+2]=vc.x;
      px[q*4+3]=vc.y; py[q*4+3]=vc.z; pz[q*4+3]=vc.w;
    }
  }

  // src cloud min/max (exact: fmin/fmax order-independent), block owns cloud
  if (cloud < B_){
    float mn0=3.4e38f,mn1=3.4e38f,mn2=3.4e38f, mx0=-3.4e38f,mx1=-3.4e38f,mx2=-3.4e38f;
    #pragma unroll
    for (int k=0;k<16;k++){
      mn0=fminf(mn0,px[k]); mn1=fminf(mn1,py[k]); mn2=fminf(mn2,pz[k]);
      mx0=fmaxf(mx0,px[k]); mx1=fmaxf(mx1,py[k]); mx2=fmaxf(mx2,pz[k]);
    }
    #pragma unroll
    for (int m=1;m<64;m<<=1){
      mn0=fminf(mn0,__shfl_xor(mn0,m,64)); mx0=fmaxf(mx0,__shfl_xor(mx0,m,64));
      mn1=fminf(mn1,__shfl_xor(mn1,m,64)); mx1=fmaxf(mx1,__shfl_xor(mx1,m,64));
      mn2=fminf(mn2,__shfl_xor(mn2,m,64)); mx2=fmaxf(mx2,__shfl_xor(mx2,m,64));
    }
    if (lane==0){
      red[wv*6+0]=mn0; red[wv*6+1]=mn1; red[wv*6+2]=mn2;
      red[wv*6+3]=mx0; red[wv*6+4]=mx1; red[wv*6+5]=mx2;
    }
    __syncthreads();
    if (t < 6){
      float v = red[t];
      for (int e=1;e<16;e++){
        float v2 = red[e*6+t];
        v = (t<3) ? fminf(v,v2) : fmaxf(v,v2);
      }
      if (t<3) ws[WS_PMIN + cloud*3 + t] = v;
      else     ws[WS_PMAX + cloud*3 + (t-3)] = v;
    }
  }
  __syncthreads();

  // kp-MLP: serial per-output chains (bit-identical to prior passing runs)
  const float* lat = ws + WS_LAT + cloud*128;
  if (t < 128){
    float acc = kb1[t];
    const float* w = kw1 + t*128;
    for (int c=0;c<128;c++) acc = fmaf(lat[c], w[c], acc);
    h[t] = fmaxf(acc, 0.0f);
  }
  __syncthreads();
  if (t < 48){
    float acc = kb2[t];
    const float* w = kw2 + t*128;
    for (int c=0;c<128;c++) acc = fmaf(h[c], w[c], acc);
    kpl[t] = acc;
  }
  __syncthreads();

  // dmin over 16 keypoints, j-outer (3 LDS broadcast reads per j)
  float mind[16];
  #pragma unroll
  for (int k=0;k<16;k++) mind[k] = 3.4028235e38f;
  for (int j=0;j<K_;j++){
    const float sx=kpl[j*3], sy=kpl[j*3+1], sz=kpl[j*3+2];
    #pragma unroll
    for (int k=0;k<16;k++)
      mind[k] = fminf(mind[k], dist2rn(px[k],py[k],pz[k], sx,sy,sz));
  }

  // round 0: argmax of keypoint-dmin
  float bv = -1.0f; int bi = 0; float bx=0.f, by=0.f, bz=0.f;
  #pragma unroll
  for (int k=0;k<16;k++){
    if (mind[k] > bv){ bv=mind[k]; bi=t*16+k; bx=px[k]; by=py[k]; bz=pz[k]; }
  }
  float s0, s1, s2;
  fps_round(0, t, wv, bv, bi, bx, by, bz, cv, ci, cx, cy, cz, ws, out, cloud, s0, s1, s2);

  // round 1: mind = dist to sel0 (REPLACE, matches reference)
  bv = -1.0f; bi = 0;
  #pragma unroll
  for (int k=0;k<16;k++){
    float d = dist2rn(px[k],py[k],pz[k], s0,s1,s2);
    mind[k] = d;
    if (d > bv){ bv=d; bi=t*16+k; bx=px[k]; by=py[k]; bz=pz[k]; }
  }
  fps_round(1, t, wv, bv, bi, bx, by, bz, cv, ci, cx, cy, cz, ws, out, cloud, s0, s1, s2);

  // rounds 2..15: mind = fmin(mind, dist to last sel)
  for (int r=2; r<K_; ++r){
    bv = -1.0f; bi = 0;
    #pragma unroll
    for (int k=0;k<16;k++){
      float d = dist2rn(px[k],py[k],pz[k], s0,s1,s2);
      float m = fminf(mind[k], d);
      mind[k] = m;
      if (m > bv){ bv=m; bi=t*16+k; bx=px[k]; by=py[k]; bz=pz[k]; }
    }
    fps_round(r, t, wv, bv, bi, bx, by, bz, cv, ci, cx, cy, cz, ws, out, cloud, s0, s1, s2);
  }
}

// ---------------- cage MLP (redundant per block) + trilinear deform -----------
// cage_mlp folded in: each block recomputes cf[1536] from WS_SEL (deterministic,
// chains identical to the old cage_mlp_kernel) — removes one kernel launch with
// no cross-block sync. Grid (16,16): 256 blocks, 4 points/thread.
__global__ __launch_bounds__(256) void deform_kernel(const float* __restrict__ src,
                                                     const float* __restrict__ cw1,
                                                     const float* __restrict__ cb1,
                                                     const float* __restrict__ cw2,
                                                     const float* __restrict__ cb2,
                                                     const float* __restrict__ ws,
                                                     float* __restrict__ out){
  const int b = blockIdx.y;
  const int t = threadIdx.x;
  __shared__ float cf[1536];
  __shared__ float diff[48];
  __shared__ float hh[128];

  if (t<48) diff[t] = __fsub_rn(ws[WS_SEL + (B_+b)*48 + t], ws[WS_SEL + b*48 + t]);
  __syncthreads();
  if (t<128){
    const float* w = cw1 + t*48;
    float acc = cb1[t];
    for (int j=0;j<48;j++) acc = fmaf(diff[j], w[j], acc);
    hh[t] = fmaxf(acc, 0.0f);
  }
  __syncthreads();
  for (int o = t; o < 1536; o += 256){
    const float* w = cw2 + o*128;
    float acc = cb2[o];
    for (int c=0;c<128;c++) acc = fmaf(hh[c], w[c], acc);
    int flat = o/3, coord = o - flat*3;
    int u = flat>>6, v=(flat>>3)&7, z=flat&7;
    int g = (coord==0)?u:((coord==1)?v:z);
    float gv = (g==7)?1.0f:(float)g*(1.0f/7.0f);
    cf[o] = gv + acc;
  }
  __syncthreads();

  const float mn0 = ws[WS_PMIN+b*3+0], mn1 = ws[WS_PMIN+b*3+1], mn2 = ws[WS_PMIN+b*3+2];
  const float mx0 = ws[WS_PMAX+b*3+0], mx1 = ws[WS_PMAX+b*3+1], mx2 = ws[WS_PMAX+b*3+2];

  #pragma unroll
  for (int k=0;k<4;k++){
    const int n = blockIdx.x*1024 + k*256 + t;
    const float* p = src + ((size_t)b*N_ + n)*3;
    float pt[3]; int id[3]; float w[3];
    #pragma unroll
    for (int c=0;c<3;c++){
      float pv = p[c];
      float mnv = (c==0)?mn0:((c==1)?mn1:mn2);
      float mxv = (c==0)?mx0:((c==1)?mx1:mx2);
      float denom = __fadd_rn(__fsub_rn(mxv, mnv), 1e-6f);
      float tc = __fmul_rn(__fdiv_rn(__fsub_rn(pv, mnv), denom), 7.0f);
      int ic = (int)tc; ic = min(max(ic,0),6);
      pt[c]=pv; id[c]=ic; w[c]=__fsub_rn(tc, (float)ic);
    }
    const int flat = (id[0]<<6) + (id[1]<<3) + id[2];
    const float* c000 = cf + flat*3;
    const float wx=w[0], wy=w[1], wz=w[2];
    const float ux=__fsub_rn(1.0f,wx), uy=__fsub_rn(1.0f,wy), uz=__fsub_rn(1.0f,wz);
    const float w000=__fmul_rn(__fmul_rn(ux,uy),uz);
    const float w100=__fmul_rn(__fmul_rn(wx,uy),uz);
    const float w010=__fmul_rn(__fmul_rn(ux,wy),uz);
    const float w110=__fmul_rn(__fmul_rn(wx,wy),uz);
    const float w001=__fmul_rn(__fmul_rn(ux,uy),wz);
    const float w101=__fmul_rn(__fmul_rn(wx,uy),wz);
    const float w011=__fmul_rn(__fmul_rn(ux,wy),wz);
    const float w111=__fmul_rn(__fmul_rn(wx,wy),wz);
    #pragma unroll
    for (int c=0;c<3;c++){
      float d = __fmul_rn(w000, c000[c]);
      d = __fadd_rn(d, __fmul_rn(w100, c000[192+c]));
      d = __fadd_rn(d, __fmul_rn(w010, c000[24+c]));
      d = __fadd_rn(d, __fmul_rn(w110, c000[216+c]));
      d = __fadd_rn(d, __fmul_rn(w001, c000[3+c]));
      d = __fadd_rn(d, __fmul_rn(w101, c000[195+c]));
      d = __fadd_rn(d, __fmul_rn(w011, c000[27+c]));
      d = __fadd_rn(d, __fmul_rn(w111, c000[219+c]));
      out[((size_t)b*N_+n)*3 + c] = __fadd_rn(pt[c], d);
    }
  }
}

// ---------------- launch ------------------------------------------------------
extern "C" void kernel_launch(void* const* d_in, const int* in_sizes, int n_in,
                              void* d_out, int out_size, void* d_ws, size_t ws_size,
                              hipStream_t stream){
  const float* src = (const float*)d_in[0];
  const float* tgt = (const float*)d_in[1];
  float* ws = (float*)d_ws;
  float* out = (float*)d_out;

  EncW ew;
  ew.w1 =(const float*)d_in[2];  ew.b1 =(const float*)d_in[3];
  ew.g1 =(const float*)d_in[4];  ew.be1=(const float*)d_in[5];
  ew.m1 =(const float*)d_in[6];  ew.v1 =(const float*)d_in[7];
  ew.w2 =(const float*)d_in[8];  ew.b2 =(const float*)d_in[9];
  ew.m2 =(const float*)d_in[12]; ew.v2 =(const float*)d_in[13];
  ew.g2 =(const float*)d_in[10]; ew.be2=(const float*)d_in[11];
  ew.w3 =(const float*)d_in[14]; ew.b3 =(const float*)d_in[15];
  ew.g3 =(const float*)d_in[16]; ew.be3=(const float*)d_in[17];
  ew.m3 =(const float*)d_in[18]; ew.v3 =(const float*)d_in[19];

  prep_kernel<<<128, 256, 0, stream>>>(ew, ws);
  encode_kernel<<<dim3(256,32), 256, 0, stream>>>(src, tgt, ws, ws + WS_LAT);
  fps_kernel<<<32, 1024, 0, stream>>>(src, tgt,
      (const float*)d_in[20], (const float*)d_in[21],
      (const float*)d_in[22], (const float*)d_in[23], ws, out);
  deform_kernel<<<dim3(16,16), 256, 0, stream>>>(src,
      (const float*)d_in[24], (const float*)d_in[25],
      (const float*)d_in[26], (const float*)d_in[27], ws, out);
}

// Round 8
// 297.870 us; speedup vs baseline: 1.5075x; 1.0017x over previous
//
#include <hip/hip_runtime.h>

#define B_ 16
#define N_ 16384
#define K_ 16

// ---- workspace layout (float offsets) ----
enum : int {
  WS_LAT  = 0,      // 32 x 128 latent (f32, atomicMax-as-uint, relu>=0)
  WS_SEL  = 5632,   // 32 x 48 selected keypoints
  WS_PMIN = 7168,   // 16 x 3
  WS_PMAX = 7216,   // 16 x 3
  WS_CF   = 7264,   // (unused; cage corners computed in deform)
  WS_W1F  = 31840,  // 64 x 3  bn-folded (fp32)
  WS_B1F  = 32032,  // 64
  // split-f16 B-fragment tables (32x32x16 MFMA layout), built by prep:
  WS_WB2H = 32096,  // 8192 f16: layer2 B hi frags [wn*4+kt][lane][8]
  WS_WB2L = 36192,  // 8192 f16
  WS_B2F  = 40288,  // 128 fp32 folded bias
  WS_WB3H = 40416,  // 16384 f16: layer3 B hi frags [wn*8+kt][lane][8]
  WS_B3F  = 56800,  // 128 fp32 folded bias
  WS_WB3L = 56928,  // 16384 f16
  WS_END  = 73312
};

enum : int { OUT_DEF=0, OUT_SRCKP=786432, OUT_TGTKP=787200 };

typedef _Float16 f16x8 __attribute__((ext_vector_type(8)));
typedef _Float16 f16x2 __attribute__((ext_vector_type(2)));
typedef float    f32x16 __attribute__((ext_vector_type(16)));

__device__ __forceinline__ float dist2rn(float px,float py,float pz,float sx,float sy,float sz){
  float dx=__fsub_rn(px,sx), dy=__fsub_rn(py,sy), dz=__fsub_rn(pz,sz);
  return __fadd_rn(__fadd_rn(__fmul_rn(dx,dx),__fmul_rn(dy,dy)),__fmul_rn(dz,dz));
}

// ---------------- prep: fold BN into encoder weights + split-f16 frags --------
struct EncW {
  const float *w1,*b1,*g1,*be1,*m1,*v1;
  const float *w2,*b2,*g2,*be2,*m2,*v2;
  const float *w3,*b3,*g3,*be3,*m3,*v3;
};

__device__ __forceinline__ float bn_scale(const float* g, const float* v, int ch){
  return g[ch] * (1.0f / sqrtf(v[ch] + 1e-5f));
}

__global__ void prep_kernel(EncW a, float* ws){
  const int stride = gridDim.x*blockDim.x;
  const int tid = blockIdx.x*blockDim.x + threadIdx.x;
  for (int i=tid;i<4096;i+=stride)            // zero latent (atomicMax target)
    ws[WS_LAT+i] = 0.0f;
  for (int i=tid;i<192;i+=stride){            // W1F
    int o=i/3;
    ws[WS_W1F+i] = a.w1[i] * bn_scale(a.g1,a.v1,o);
  }
  for (int i=tid;i<64;i+=stride){             // B1F
    float s = bn_scale(a.g1,a.v1,i);
    ws[WS_B1F+i] = (a.b1[i] - a.m1[i])*s + a.be1[i];
  }
  // layer2 B-frags for 32x32x16: lane l holds B[k=kt*16+(l>>5)*8+j][col=wn*32+(l&31)]
  for (int i=tid;i<8192;i+=stride){
    int j = i & 7, frag = i >> 3;
    int l = frag & 63, wk = frag >> 6;        // wk = wn*4 + kt, <16
    int kt = wk & 3, wn = wk >> 2;
    int c = kt*16 + ((l>>5)<<3) + j;          // 0..63 in-channel (K)
    int o = wn*32 + (l&31);                   // 0..127 out-channel (N)
    float v = a.w2[o*64+c] * bn_scale(a.g2,a.v2,o);
    _Float16 h = (_Float16)v;
    ((_Float16*)(ws+WS_WB2H))[i] = h;
    ((_Float16*)(ws+WS_WB2L))[i] = (_Float16)(v - (float)h);
  }
  for (int i=tid;i<128;i+=stride){
    float s = bn_scale(a.g2,a.v2,i);
    ws[WS_B2F+i] = (a.b2[i] - a.m2[i])*s + a.be2[i];
  }
  // layer3 B-frags (bounded correctly: 16384 elements = 128x128)
  for (int i=tid;i<16384;i+=stride){
    int j = i & 7, frag = i >> 3;
    int l = frag & 63, wk = frag >> 6;        // wk = wn*8 + kt, <32
    int kt = wk & 7, wn = wk >> 3;
    int c = kt*16 + ((l>>5)<<3) + j;          // 0..127 in-channel (K)
    int o = wn*32 + (l&31);                   // 0..127 out-channel (N)
    float v = a.w3[o*128+c] * bn_scale(a.g3,a.v3,o);
    _Float16 h = (_Float16)v;
    ((_Float16*)(ws+WS_WB3H))[i] = h;
    ((_Float16*)(ws+WS_WB3L))[i] = (_Float16)(v - (float)h);
  }
  for (int i=tid;i<128;i+=stride){
    float s = bn_scale(a.g3,a.v3,i);
    ws[WS_B3F+i] = (a.b3[i] - a.m3[i])*s + a.be3[i];
  }
}

// ---------------- encoder v14: 32x32x16 MFMA (half the MFMA instructions) -----
// R7 post-mortem: MFMA issue ~33us at 5cyc/16x16x32; 32x32x16 does 2x MACs at
// ~8cyc -> 72 MFMA/wave vs 144, ~20% less MFMA issue + 15% better pipe rate
// (2382 vs 2075 TF ubench). A/B frag: lane l -> row/col=l&31, k=(l>>5)*8+j.
// C/D: col=lane&31, row=(reg&3)+8*(reg>>2)+4*(lane>>5) [m74/m101 verified].
// Addresses hoisted to per-lane bases + static immediates (v13 technique).
__global__ __launch_bounds__(256, 5) void encode_kernel(const float* __restrict__ src,
                                                        const float* __restrict__ tgt,
                                                        const float* __restrict__ ws,
                                                        float* __restrict__ lat){
  const int cloud = blockIdx.y;
  const int tile  = blockIdx.x;              // 256 tiles/cloud, 64 pts each
  const int t = threadIdx.x;
  const int lane = t & 63;
  const int wn = __builtin_amdgcn_readfirstlane(t >> 6);   // 0..3: cols wn*32..+31
  const int l31 = lane & 31;
  const int hb  = lane >> 5;                 // 0/1: k-group / +4-row half
  const int swz = (l31 & 7) << 3;            // f16-index bits 3-5

  __shared__ alignas(16) _Float16 A[16384];  // 32KB
  // AH1 = +0 (8KB f16 idx), AL1 = +8192B; overlay AH2 = +0, AL2 = +16384B

  const float* base = ((cloud < B_) ? (src + (size_t)cloud*N_*3)
                                    : (tgt + (size_t)(cloud-B_)*N_*3))
                      + (size_t)tile*64*3;

  // ---- prefetch layer2 B-frags (latency hides under layer1) ----
  f16x8 b2h[4], b2l[4];
  {
    const _Float16* wb2h = (const _Float16*)(ws + WS_WB2H);
    const _Float16* wb2l = (const _Float16*)(ws + WS_WB2L);
    #pragma unroll
    for (int kt=0; kt<4; kt++){
      const int fi = ((wn*4 + kt)*64 + lane)*8;
      b2h[kt] = *(const f16x8*)(wb2h + fi);
      b2l[kt] = *(const f16x8*)(wb2l + fi);
    }
  }

  // ---- layer 1 (3->64), fp32 VALU (chain identical to v12/v13) ----
  {
    const int pt = t >> 2, q = t & 3;        // pt 0..63
    const float x = base[pt*3+0], y = base[pt*3+1], z = base[pt*3+2];
    const float* w1 = ws + WS_W1F;
    const float* b1 = ws + WS_B1F;
    const int swz1 = (pt & 7) << 3;
    _Float16* AH1 = A;
    _Float16* AL1 = A + 4096;
    #pragma unroll
    for (int cc = 0; cc < 16; cc += 2){
      const int o = q*16 + cc;
      float v0 = fmaf(w1[o*3+2], z, fmaf(w1[o*3+1], y, w1[o*3+0]*x)) + b1[o];
      float v1 = fmaf(w1[o*3+5], z, fmaf(w1[o*3+4], y, w1[o*3+3]*x)) + b1[o+1];
      v0 = fmaxf(v0, 0.0f); v1 = fmaxf(v1, 0.0f);
      f16x2 h, l;
      h[0] = (_Float16)v0;              h[1] = (_Float16)v1;
      l[0] = (_Float16)(v0 - (float)h[0]); l[1] = (_Float16)(v1 - (float)h[1]);
      const int idx = (pt*64 + o) ^ swz1;
      *(f16x2*)&AH1[idx] = h;
      *(f16x2*)&AL1[idx] = l;
    }
  }

  // per-kt within-row byte offsets (shared by layer2/layer3 reads)
  int koff[8];
  #pragma unroll
  for (int kt=0; kt<8; kt++) koff[kt] = (((kt*16) | (hb*8)) ^ swz) << 1;

  __syncthreads();

  // ---- layer 2 (64->128): M64 K64 N128, 3-term split, 32x32x16 ----
  f32x16 acc2[2];
  #pragma unroll
  for (int e=0;e<16;e++){ acc2[0][e]=0.0f; acc2[1][e]=0.0f; }
  {
    const char* pA2 = (const char*)A + l31*128;   // row stride 128B (64 f16)
    #pragma unroll
    for (int kt=0; kt<4; kt++){
      #pragma unroll
      for (int m=0;m<2;m++){
        const f16x8 ah = *(const f16x8*)(pA2 + m*4096 + koff[kt]);
        const f16x8 al = *(const f16x8*)(pA2 + m*4096 + koff[kt] + 8192);
        acc2[m] = __builtin_amdgcn_mfma_f32_32x32x16_f16(ah, b2h[kt], acc2[m], 0,0,0);
        acc2[m] = __builtin_amdgcn_mfma_f32_32x32x16_f16(ah, b2l[kt], acc2[m], 0,0,0);
        acc2[m] = __builtin_amdgcn_mfma_f32_32x32x16_f16(al, b2h[kt], acc2[m], 0,0,0);
      }
    }
  }
  __syncthreads();   // all h1 reads complete before overlay write

  // ---- h2 = relu(acc2 + b2): split hi/lo -> LDS (hoisted addresses) ----
  const int ch = wn*32 + l31;
  {
    const float b = ws[WS_B2F + ch];
    char* pWr[4];
    #pragma unroll
    for (int r4=0;r4<4;r4++)
      pWr[r4] = (char*)A + (r4 + 4*hb)*256 + ((ch ^ ((r4 + 4*hb) << 3)) << 1);
    #pragma unroll
    for (int r4=0;r4<4;r4++){
      #pragma unroll
      for (int rq=0;rq<4;rq++){
        const int reg = rq*4 + r4;           // reg&3=r4, reg>>2=rq
        #pragma unroll
        for (int m=0;m<2;m++){
          const float v = fmaxf(acc2[m][reg] + b, 0.0f);
          const _Float16 hi = (_Float16)v;
          const _Float16 lo = (_Float16)(v - (float)hi);
          char* pw = pWr[r4] + rq*2048 + m*8192;   // row=m*32+r4+8rq+4hb, stride 256B
          *(_Float16*)(pw) = hi;
          *(_Float16*)(pw + 16384) = lo;
        }
      }
    }
  }
  __syncthreads();

  // ---- layer 3 (128->128): M64 K128 N128, 3-term split, 32x32x16 ----
  f32x16 acc3[2];
  #pragma unroll
  for (int e=0;e<16;e++){ acc3[0][e]=0.0f; acc3[1][e]=0.0f; }
  {
    const _Float16* wb3h = (const _Float16*)(ws + WS_WB3H);
    const _Float16* wb3l = (const _Float16*)(ws + WS_WB3L);
    const char* pA3 = (const char*)A + l31*256;   // row stride 256B (128 f16)
    #pragma unroll
    for (int kt=0; kt<8; kt++){
      const int fi = ((wn*8 + kt)*64 + lane)*8;
      const f16x8 bh = *(const f16x8*)(wb3h + fi);
      const f16x8 bl = *(const f16x8*)(wb3l + fi);
      #pragma unroll
      for (int m=0;m<2;m++){
        const f16x8 ah = *(const f16x8*)(pA3 + m*8192 + koff[kt]);
        const f16x8 al = *(const f16x8*)(pA3 + m*8192 + koff[kt] + 16384);
        acc3[m] = __builtin_amdgcn_mfma_f32_32x32x16_f16(ah, bh, acc3[m], 0,0,0);
        acc3[m] = __builtin_amdgcn_mfma_f32_32x32x16_f16(ah, bl, acc3[m], 0,0,0);
        acc3[m] = __builtin_amdgcn_mfma_f32_32x32x16_f16(al, bh, acc3[m], 0,0,0);
      }
    }
  }

  // epilogue: bias+relu, max over the 32 owned (row,ch) values, pair-shfl, atomic
  {
    const float b = ws[WS_B3F + ch];
    float x = 0.0f;                          // relu floor
    #pragma unroll
    for (int m=0;m<2;m++){
      #pragma unroll
      for (int r=0;r<16;r++)
        x = fmaxf(x, acc3[m][r] + b);
    }
    x = fmaxf(x, __shfl_xor(x, 32, 64));
    if (lane < 32)
      atomicMax((unsigned*)(lat + cloud*128 + ch), __float_as_uint(x));
  }
}

// ---------------- FPS v3 (unchanged from R7, passing) --------------------------
__device__ __forceinline__ void fps_round(int r, int t, int wv,
                                          float bv, int bi, float bx, float by, float bz,
                                          float (*cv)[16], int (*ci)[16],
                                          float (*cx)[16], float (*cy)[16], float (*cz)[16],
                                          float* ws, float* out, int cloud,
                                          float& s0, float& s1, float& s2){
  float v = bv; int i = bi;
  #pragma unroll
  for (int m=1;m<64;m<<=1){
    float v2=__shfl_xor(v,m,64); int i2=__shfl_xor(i,m,64);
    if (v2 > v || (v2 == v && i2 < i)){ v=v2; i=i2; }
  }
  const int p = r & 1;
  if ((i >> 4) == t){ cv[p][wv]=v; ci[p][wv]=i; cx[p][wv]=bx; cy[p][wv]=by; cz[p][wv]=bz; }
  __syncthreads();
  float wvv = cv[p][0]; int wi = ci[p][0]; int slot = 0;
  #pragma unroll
  for (int e=1;e<16;e++){
    float v2=cv[p][e]; int i2=ci[p][e];
    if (v2 > wvv || (v2 == wvv && i2 < wi)){ wvv=v2; wi=i2; slot=e; }
  }
  s0 = cx[p][slot]; s1 = cy[p][slot]; s2 = cz[p][slot];
  if (t == 0){
    float* sw = ws + WS_SEL + cloud*48 + r*3;
    sw[0]=s0; sw[1]=s1; sw[2]=s2;
    size_t o = (cloud<B_) ? (size_t)(OUT_SRCKP + cloud*48 + r*3)
                          : (size_t)(OUT_TGTKP + (cloud-B_)*48 + r*3);
    out[o]=s0; out[o+1]=s1; out[o+2]=s2;
  }
}

__global__ __launch_bounds__(1024, 4) void fps_kernel(const float* __restrict__ src,
                                                      const float* __restrict__ tgt,
                                                      const float* __restrict__ kw1,
                                                      const float* __restrict__ kb1,
                                                      const float* __restrict__ kw2,
                                                      const float* __restrict__ kb2,
                                                      float* ws, float* out){
  const int cloud = blockIdx.x; const int t = threadIdx.x;
  const int wv = t >> 6;
  const int lane = t & 63;
  const float* base = (cloud < B_) ? (src + (size_t)cloud*N_*3)
                                   : (tgt + (size_t)cloud*N_*3 - (size_t)B_*N_*3);
  __shared__ float kpl[48];
  __shared__ float h[128];
  __shared__ float cv[2][16]; __shared__ int ci[2][16];
  __shared__ float cx[2][16]; __shared__ float cy[2][16]; __shared__ float cz[2][16];
  __shared__ float red[96];

  // 16 consecutive points/thread via 12 float4 (coalesced), direct unpack
  float px[16], py[16], pz[16];
  {
    const float4* b4 = (const float4*)(base + (size_t)t*48);
    #pragma unroll
    for (int q=0;q<4;q++){
      float4 va=b4[q*3], vb=b4[q*3+1], vc=b4[q*3+2];
      px[q*4  ]=va.x; py[q*4  ]=va.y; pz[q*4  ]=va.z;
      px[q*4+1]=va.w; py[q*4+1]=vb.x; pz[q*4+1]=vb.y;
      px[q*4+2]=vb.z; py[q*4+2]=vb.w; pz[q*4+2]=vc.x;
      px[q*4+3]=vc.y; py[q*4+3]=vc.z; pz[q*4+3]=vc.w;
    }
  }

  // src cloud min/max (exact: fmin/fmax order-independent)
  if (cloud < B_){
    float mn0=3.4e38f,mn1=3.4e38f,mn2=3.4e38f, mx0=-3.4e38f,mx1=-3.4e38f,mx2=-3.4e38f;
    #pragma unroll
    for (int k=0;k<16;k++){
      mn0=fminf(mn0,px[k]); mn1=fminf(mn1,py[k]); mn2=fminf(mn2,pz[k]);
      mx0=fmaxf(mx0,px[k]); mx1=fmaxf(mx1,py[k]); mx2=fmaxf(mx2,pz[k]);
    }
    #pragma unroll
    for (int m=1;m<64;m<<=1){
      mn0=fminf(mn0,__shfl_xor(mn0,m,64)); mx0=fmaxf(mx0,__shfl_xor(mx0,m,64));
      mn1=fminf(mn1,__shfl_xor(mn1,m,64)); mx1=fmaxf(mx1,__shfl_xor(mx1,m,64));
      mn2=fminf(mn2,__shfl_xor(mn2,m,64)); mx2=fmaxf(mx2,__shfl_xor(mx2,m,64));
    }
    if (lane==0){
      red[wv*6+0]=mn0; red[wv*6+1]=mn1; red[wv*6+2]=mn2;
      red[wv*6+3]=mx0; red[wv*6+4]=mx1; red[wv*6+5]=mx2;
    }
    __syncthreads();
    if (t < 6){
      float v = red[t];
      for (int e=1;e<16;e++){
        float v2 = red[e*6+t];
        v = (t<3) ? fminf(v,v2) : fmaxf(v,v2);
      }
      if (t<3) ws[WS_PMIN + cloud*3 + t] = v;
      else     ws[WS_PMAX + cloud*3 + (t-3)] = v;
    }
  }
  __syncthreads();

  // kp-MLP: serial per-output chains (bit-identical to prior passing runs)
  const float* lat = ws + WS_LAT + cloud*128;
  if (t < 128){
    float acc = kb1[t];
    const float* w = kw1 + t*128;
    for (int c=0;c<128;c++) acc = fmaf(lat[c], w[c], acc);
    h[t] = fmaxf(acc, 0.0f);
  }
  __syncthreads();
  if (t < 48){
    float acc = kb2[t];
    const float* w = kw2 + t*128;
    for (int c=0;c<128;c++) acc = fmaf(h[c], w[c], acc);
    kpl[t] = acc;
  }
  __syncthreads();

  // dmin over 16 keypoints, j-outer
  float mind[16];
  #pragma unroll
  for (int k=0;k<16;k++) mind[k] = 3.4028235e38f;
  for (int j=0;j<K_;j++){
    const float sx=kpl[j*3], sy=kpl[j*3+1], sz=kpl[j*3+2];
    #pragma unroll
    for (int k=0;k<16;k++)
      mind[k] = fminf(mind[k], dist2rn(px[k],py[k],pz[k], sx,sy,sz));
  }

  // round 0: argmax of keypoint-dmin
  float bv = -1.0f; int bi = 0; float bx=0.f, by=0.f, bz=0.f;
  #pragma unroll
  for (int k=0;k<16;k++){
    if (mind[k] > bv){ bv=mind[k]; bi=t*16+k; bx=px[k]; by=py[k]; bz=pz[k]; }
  }
  float s0, s1, s2;
  fps_round(0, t, wv, bv, bi, bx, by, bz, cv, ci, cx, cy, cz, ws, out, cloud, s0, s1, s2);

  // round 1: REPLACE (matches reference)
  bv = -1.0f; bi = 0;
  #pragma unroll
  for (int k=0;k<16;k++){
    float d = dist2rn(px[k],py[k],pz[k], s0,s1,s2);
    mind[k] = d;
    if (d > bv){ bv=d; bi=t*16+k; bx=px[k]; by=py[k]; bz=pz[k]; }
  }
  fps_round(1, t, wv, bv, bi, bx, by, bz, cv, ci, cx, cy, cz, ws, out, cloud, s0, s1, s2);

  // rounds 2..15
  for (int r=2; r<K_; ++r){
    bv = -1.0f; bi = 0;
    #pragma unroll
    for (int k=0;k<16;k++){
      float d = dist2rn(px[k],py[k],pz[k], s0,s1,s2);
      float m = fminf(mind[k], d);
      mind[k] = m;
      if (m > bv){ bv=m; bi=t*16+k; bx=px[k]; by=py[k]; bz=pz[k]; }
    }
    fps_round(r, t, wv, bv, bi, bx, by, bz, cv, ci, cx, cy, cz, ws, out, cloud, s0, s1, s2);
  }
}

// ---------------- cage MLP (redundant per block) + trilinear deform -----------
__global__ __launch_bounds__(256) void deform_kernel(const float* __restrict__ src,
                                                     const float* __restrict__ cw1,
                                                     const float* __restrict__ cb1,
                                                     const float* __restrict__ cw2,
                                                     const float* __restrict__ cb2,
                                                     const float* __restrict__ ws,
                                                     float* __restrict__ out){
  const int b = blockIdx.y;
  const int t = threadIdx.x;
  __shared__ float cf[1536];
  __shared__ float diff[48];
  __shared__ float hh[128];

  if (t<48) diff[t] = __fsub_rn(ws[WS_SEL + (B_+b)*48 + t], ws[WS_SEL + b*48 + t]);
  __syncthreads();
  if (t<128){
    const float* w = cw1 + t*48;
    float acc = cb1[t];
    for (int j=0;j<48;j++) acc = fmaf(diff[j], w[j], acc);
    hh[t] = fmaxf(acc, 0.0f);
  }
  __syncthreads();
  for (int o = t; o < 1536; o += 256){
    const float* w = cw2 + o*128;
    float acc = cb2[o];
    for (int c=0;c<128;c++) acc = fmaf(hh[c], w[c], acc);
    int flat = o/3, coord = o - flat*3;
    int u = flat>>6, v=(flat>>3)&7, z=flat&7;
    int g = (coord==0)?u:((coord==1)?v:z);
    float gv = (g==7)?1.0f:(float)g*(1.0f/7.0f);
    cf[o] = gv + acc;
  }
  __syncthreads();

  const float mn0 = ws[WS_PMIN+b*3+0], mn1 = ws[WS_PMIN+b*3+1], mn2 = ws[WS_PMIN+b*3+2];
  const float mx0 = ws[WS_PMAX+b*3+0], mx1 = ws[WS_PMAX+b*3+1], mx2 = ws[WS_PMAX+b*3+2];

  #pragma unroll
  for (int k=0;k<4;k++){
    const int n = blockIdx.x*1024 + k*256 + t;
    const float* p = src + ((size_t)b*N_ + n)*3;
    float pt[3]; int id[3]; float w[3];
    #pragma unroll
    for (int c=0;c<3;c++){
      float pv = p[c];
      float mnv = (c==0)?mn0:((c==1)?mn1:mn2);
      float mxv = (c==0)?mx0:((c==1)?mx1:mx2);
      float denom = __fadd_rn(__fsub_rn(mxv, mnv), 1e-6f);
      float tc = __fmul_rn(__fdiv_rn(__fsub_rn(pv, mnv), denom), 7.0f);
      int ic = (int)tc; ic = min(max(ic,0),6);
      pt[c]=pv; id[c]=ic; w[c]=__fsub_rn(tc, (float)ic);
    }
    const int flat = (id[0]<<6) + (id[1]<<3) + id[2];
    const float* c000 = cf + flat*3;
    const float wx=w[0], wy=w[1], wz=w[2];
    const float ux=__fsub_rn(1.0f,wx), uy=__fsub_rn(1.0f,wy), uz=__fsub_rn(1.0f,wz);
    const float w000=__fmul_rn(__fmul_rn(ux,uy),uz);
    const float w100=__fmul_rn(__fmul_rn(wx,uy),uz);
    const float w010=__fmul_rn(__fmul_rn(ux,wy),uz);
    const float w110=__fmul_rn(__fmul_rn(wx,wy),uz);
    const float w001=__fmul_rn(__fmul_rn(ux,uy),wz);
    const float w101=__fmul_rn(__fmul_rn(wx,uy),wz);
    const float w011=__fmul_rn(__fmul_rn(ux,wy),wz);
    const float w111=__fmul_rn(__fmul_rn(wx,wy),wz);
    #pragma unroll
    for (int c=0;c<3;c++){
      float d = __fmul_rn(w000, c000[c]);
      d = __fadd_rn(d, __fmul_rn(w100, c000[192+c]));
      d = __fadd_rn(d, __fmul_rn(w010, c000[24+c]));
      d = __fadd_rn(d, __fmul_rn(w110, c000[216+c]));
      d = __fadd_rn(d, __fmul_rn(w001, c000[3+c]));
      d = __fadd_rn(d, __fmul_rn(w101, c000[195+c]));
      d = __fadd_rn(d, __fmul_rn(w011, c000[27+c]));
      d = __fadd_rn(d, __fmul_rn(w111, c000[219+c]));
      out[((size_t)b*N_+n)*3 + c] = __fadd_rn(pt[c], d);
    }
  }
}

// ---------------- launch ------------------------------------------------------
extern "C" void kernel_launch(void* const* d_in, const int* in_sizes, int n_in,
                              void* d_out, int out_size, void* d_ws, size_t ws_size,
                              hipStream_t stream){
  const float* src = (const float*)d_in[0];
  const float* tgt = (const float*)d_in[1];
  float* ws = (float*)d_ws;
  float* out = (float*)d_out;

  EncW ew;
  ew.w1 =(const float*)d_in[2];  ew.b1 =(const float*)d_in[3];
  ew.g1 =(const float*)d_in[4];  ew.be1=(const float*)d_in[5];
  ew.m1 =(const float*)d_in[6];  ew.v1 =(const float*)d_in[7];
  ew.w2 =(const float*)d_in[8];  ew.b2 =(const float*)d_in[9];
  ew.g2 =(const float*)d_in[10]; ew.be2=(const float*)d_in[11];
  ew.m2 =(const float*)d_in[12]; ew.v2 =(const float*)d_in[13];
  ew.w3 =(const float*)d_in[14]; ew.b3 =(const float*)d_in[15];
  ew.g3 =(const float*)d_in[16]; ew.be3=(const float*)d_in[17];
  ew.m3 =(const float*)d_in[18]; ew.v3 =(const float*)d_in[19];

  prep_kernel<<<128, 256, 0, stream>>>(ew, ws);
  encode_kernel<<<dim3(256,32), 256, 0, stream>>>(src, tgt, ws, ws + WS_LAT);
  fps_kernel<<<32, 1024, 0, stream>>>(src, tgt,
      (const float*)d_in[20], (const float*)d_in[21],
      (const float*)d_in[22], (const float*)d_in[23], ws, out);
  deform_kernel<<<dim3(16,16), 256, 0, stream>>>(src,
      (const float*)d_in[24], (const float*)d_in[25],
      (const float*)d_in[26], (const float*)d_in[27], ws, out);
}

// Round 10
// 297.392 us; speedup vs baseline: 1.5099x; 1.0016x over previous
//
#include <hip/hip_runtime.h>

#define B_ 16
#define N_ 16384
#define K_ 16

// ---- workspace layout (float offsets) ----
enum : int {
  WS_LAT  = 0,      // 32 x 128 latent (f32, atomicMax-as-uint, relu>=0)
  WS_SEL  = 5632,   // 32 x 48 selected keypoints
  WS_PMIN = 7168,   // 16 x 3
  WS_PMAX = 7216,   // 16 x 3
  WS_CF   = 7264,   // (unused; cage corners computed in deform)
  WS_W1F  = 31840,  // 64 x 3  bn-folded (fp32)
  WS_B1F  = 32032,  // 64
  // split-f16 B-fragment tables (32x32x16 MFMA layout), built by prep:
  WS_WB2H = 32096,  // 8192 f16: layer2 B hi frags [wn*4+kt][lane][8]
  WS_WB2L = 36192,  // 8192 f16
  WS_B2F  = 40288,  // 128 fp32 folded bias
  WS_WB3H = 40416,  // 16384 f16: layer3 B hi frags [wn*8+kt][lane][8]
  WS_B3F  = 56800,  // 128 fp32 folded bias
  WS_WB3L = 56928,  // 16384 f16
  WS_END  = 73312
};

enum : int { OUT_DEF=0, OUT_SRCKP=786432, OUT_TGTKP=787200 };

typedef _Float16 f16x8 __attribute__((ext_vector_type(8)));
typedef _Float16 f16x2 __attribute__((ext_vector_type(2)));
typedef float    f32x16 __attribute__((ext_vector_type(16)));

__device__ __forceinline__ float dist2rn(float px,float py,float pz,float sx,float sy,float sz){
  float dx=__fsub_rn(px,sx), dy=__fsub_rn(py,sy), dz=__fsub_rn(pz,sz);
  return __fadd_rn(__fadd_rn(__fmul_rn(dx,dx),__fmul_rn(dy,dy)),__fmul_rn(dz,dz));
}

// ---------------- prep: fold BN into encoder weights + split-f16 frags --------
struct EncW {
  const float *w1,*b1,*g1,*be1,*m1,*v1;
  const float *w2,*b2,*g2,*be2,*m2,*v2;
  const float *w3,*b3,*g3,*be3,*m3,*v3;
};

__device__ __forceinline__ float bn_scale(const float* g, const float* v, int ch){
  return g[ch] * (1.0f / sqrtf(v[ch] + 1e-5f));
}

__global__ void prep_kernel(EncW a, float* ws){
  const int stride = gridDim.x*blockDim.x;
  const int tid = blockIdx.x*blockDim.x + threadIdx.x;
  for (int i=tid;i<4096;i+=stride)            // zero latent (atomicMax target)
    ws[WS_LAT+i] = 0.0f;
  for (int i=tid;i<192;i+=stride){            // W1F
    int o=i/3;
    ws[WS_W1F+i] = a.w1[i] * bn_scale(a.g1,a.v1,o);
  }
  for (int i=tid;i<64;i+=stride){             // B1F
    float s = bn_scale(a.g1,a.v1,i);
    ws[WS_B1F+i] = (a.b1[i] - a.m1[i])*s + a.be1[i];
  }
  // layer2 B-frags for 32x32x16: lane l holds B[k=kt*16+(l>>5)*8+j][col=wn*32+(l&31)]
  for (int i=tid;i<8192;i+=stride){
    int j = i & 7, frag = i >> 3;
    int l = frag & 63, wk = frag >> 6;        // wk = wn*4 + kt, <16
    int kt = wk & 3, wn = wk >> 2;
    int c = kt*16 + ((l>>5)<<3) + j;          // 0..63 in-channel (K)
    int o = wn*32 + (l&31);                   // 0..127 out-channel (N)
    float v = a.w2[o*64+c] * bn_scale(a.g2,a.v2,o);
    _Float16 h = (_Float16)v;
    ((_Float16*)(ws+WS_WB2H))[i] = h;
    ((_Float16*)(ws+WS_WB2L))[i] = (_Float16)(v - (float)h);
  }
  for (int i=tid;i<128;i+=stride){
    float s = bn_scale(a.g2,a.v2,i);
    ws[WS_B2F+i] = (a.b2[i] - a.m2[i])*s + a.be2[i];
  }
  // layer3 B-frags (16384 elements = 128x128)
  for (int i=tid;i<16384;i+=stride){
    int j = i & 7, frag = i >> 3;
    int l = frag & 63, wk = frag >> 6;        // wk = wn*8 + kt, <32
    int kt = wk & 7, wn = wk >> 3;
    int c = kt*16 + ((l>>5)<<3) + j;          // 0..127 in-channel (K)
    int o = wn*32 + (l&31);                   // 0..127 out-channel (N)
    float v = a.w3[o*128+c] * bn_scale(a.g3,a.v3,o);
    _Float16 h = (_Float16)v;
    ((_Float16*)(ws+WS_WB3H))[i] = h;
    ((_Float16*)(ws+WS_WB3L))[i] = (_Float16)(v - (float)h);
  }
  for (int i=tid;i<128;i+=stride){
    float s = bn_scale(a.g3,a.v3,i);
    ws[WS_B3F+i] = (a.b3[i] - a.m3[i])*s + a.be3[i];
  }
}

// ---------------- encoder v14 (unchanged from R8, passing) --------------------
__global__ __launch_bounds__(256, 5) void encode_kernel(const float* __restrict__ src,
                                                        const float* __restrict__ tgt,
                                                        const float* __restrict__ ws,
                                                        float* __restrict__ lat){
  const int cloud = blockIdx.y;
  const int tile  = blockIdx.x;              // 256 tiles/cloud, 64 pts each
  const int t = threadIdx.x;
  const int lane = t & 63;
  const int wn = __builtin_amdgcn_readfirstlane(t >> 6);   // 0..3: cols wn*32..+31
  const int l31 = lane & 31;
  const int hb  = lane >> 5;                 // 0/1: k-group / +4-row half
  const int swz = (l31 & 7) << 3;            // f16-index bits 3-5

  __shared__ alignas(16) _Float16 A[16384];  // 32KB

  const float* base = ((cloud < B_) ? (src + (size_t)cloud*N_*3)
                                    : (tgt + (size_t)(cloud-B_)*N_*3))
                      + (size_t)tile*64*3;

  // ---- prefetch layer2 B-frags (latency hides under layer1) ----
  f16x8 b2h[4], b2l[4];
  {
    const _Float16* wb2h = (const _Float16*)(ws + WS_WB2H);
    const _Float16* wb2l = (const _Float16*)(ws + WS_WB2L);
    #pragma unroll
    for (int kt=0; kt<4; kt++){
      const int fi = ((wn*4 + kt)*64 + lane)*8;
      b2h[kt] = *(const f16x8*)(wb2h + fi);
      b2l[kt] = *(const f16x8*)(wb2l + fi);
    }
  }

  // ---- layer 1 (3->64), fp32 VALU ----
  {
    const int pt = t >> 2, q = t & 3;        // pt 0..63
    const float x = base[pt*3+0], y = base[pt*3+1], z = base[pt*3+2];
    const float* w1 = ws + WS_W1F;
    const float* b1 = ws + WS_B1F;
    const int swz1 = (pt & 7) << 3;
    _Float16* AH1 = A;
    _Float16* AL1 = A + 4096;
    #pragma unroll
    for (int cc = 0; cc < 16; cc += 2){
      const int o = q*16 + cc;
      float v0 = fmaf(w1[o*3+2], z, fmaf(w1[o*3+1], y, w1[o*3+0]*x)) + b1[o];
      float v1 = fmaf(w1[o*3+5], z, fmaf(w1[o*3+4], y, w1[o*3+3]*x)) + b1[o+1];
      v0 = fmaxf(v0, 0.0f); v1 = fmaxf(v1, 0.0f);
      f16x2 h, l;
      h[0] = (_Float16)v0;              h[1] = (_Float16)v1;
      l[0] = (_Float16)(v0 - (float)h[0]); l[1] = (_Float16)(v1 - (float)h[1]);
      const int idx = (pt*64 + o) ^ swz1;
      *(f16x2*)&AH1[idx] = h;
      *(f16x2*)&AL1[idx] = l;
    }
  }

  int koff[8];
  #pragma unroll
  for (int kt=0; kt<8; kt++) koff[kt] = (((kt*16) | (hb*8)) ^ swz) << 1;

  __syncthreads();

  // ---- layer 2 (64->128): 3-term split, 32x32x16 ----
  f32x16 acc2[2];
  #pragma unroll
  for (int e=0;e<16;e++){ acc2[0][e]=0.0f; acc2[1][e]=0.0f; }
  {
    const char* pA2 = (const char*)A + l31*128;
    #pragma unroll
    for (int kt=0; kt<4; kt++){
      #pragma unroll
      for (int m=0;m<2;m++){
        const f16x8 ah = *(const f16x8*)(pA2 + m*4096 + koff[kt]);
        const f16x8 al = *(const f16x8*)(pA2 + m*4096 + koff[kt] + 8192);
        acc2[m] = __builtin_amdgcn_mfma_f32_32x32x16_f16(ah, b2h[kt], acc2[m], 0,0,0);
        acc2[m] = __builtin_amdgcn_mfma_f32_32x32x16_f16(ah, b2l[kt], acc2[m], 0,0,0);
        acc2[m] = __builtin_amdgcn_mfma_f32_32x32x16_f16(al, b2h[kt], acc2[m], 0,0,0);
      }
    }
  }
  __syncthreads();

  // ---- h2 = relu(acc2 + b2): split hi/lo -> LDS ----
  const int ch = wn*32 + l31;
  {
    const float b = ws[WS_B2F + ch];
    char* pWr[4];
    #pragma unroll
    for (int r4=0;r4<4;r4++)
      pWr[r4] = (char*)A + (r4 + 4*hb)*256 + ((ch ^ ((r4 + 4*hb) << 3)) << 1);
    #pragma unroll
    for (int r4=0;r4<4;r4++){
      #pragma unroll
      for (int rq=0;rq<4;rq++){
        const int reg = rq*4 + r4;
        #pragma unroll
        for (int m=0;m<2;m++){
          const float v = fmaxf(acc2[m][reg] + b, 0.0f);
          const _Float16 hi = (_Float16)v;
          const _Float16 lo = (_Float16)(v - (float)hi);
          char* pw = pWr[r4] + rq*2048 + m*8192;
          *(_Float16*)(pw) = hi;
          *(_Float16*)(pw + 16384) = lo;
        }
      }
    }
  }
  __syncthreads();

  // ---- layer 3 (128->128): 3-term split, 32x32x16 ----
  f32x16 acc3[2];
  #pragma unroll
  for (int e=0;e<16;e++){ acc3[0][e]=0.0f; acc3[1][e]=0.0f; }
  {
    const _Float16* wb3h = (const _Float16*)(ws + WS_WB3H);
    const _Float16* wb3l = (const _Float16*)(ws + WS_WB3L);
    const char* pA3 = (const char*)A + l31*256;
    #pragma unroll
    for (int kt=0; kt<8; kt++){
      const int fi = ((wn*8 + kt)*64 + lane)*8;
      const f16x8 bh = *(const f16x8*)(wb3h + fi);
      const f16x8 bl = *(const f16x8*)(wb3l + fi);
      #pragma unroll
      for (int m=0;m<2;m++){
        const f16x8 ah = *(const f16x8*)(pA3 + m*8192 + koff[kt]);
        const f16x8 al = *(const f16x8*)(pA3 + m*8192 + koff[kt] + 16384);
        acc3[m] = __builtin_amdgcn_mfma_f32_32x32x16_f16(ah, bh, acc3[m], 0,0,0);
        acc3[m] = __builtin_amdgcn_mfma_f32_32x32x16_f16(ah, bl, acc3[m], 0,0,0);
        acc3[m] = __builtin_amdgcn_mfma_f32_32x32x16_f16(al, bh, acc3[m], 0,0,0);
      }
    }
  }

  // epilogue
  {
    const float b = ws[WS_B3F + ch];
    float x = 0.0f;
    #pragma unroll
    for (int m=0;m<2;m++){
      #pragma unroll
      for (int r=0;r<16;r++)
        x = fmaxf(x, acc3[m][r] + b);
    }
    x = fmaxf(x, __shfl_xor(x, 32, 64));
    if (lane < 32)
      atomicMax((unsigned*)(lat + cloud*128 + ch), __float_as_uint(x));
  }
}

// ---------------- FPS v4: load-pipelined MLP chains, early point-load issue ---
// R8 theory: fps ~94us (inferred from R4's tail accounting) dominated by
// latency-exposed serial load+fmaf loops (128 iters, 1 load in flight).
// v4 batches loads as float4 with partial unroll -- FMA ORDER UNCHANGED
// (bit-identical kpl -> identical selections) -- and issues the 12 point
// float4 loads at kernel top, consuming them after the kp-MLP phases.
__device__ __forceinline__ void fps_round(int r, int t, int wv,
                                          float bv, int bi, float bx, float by, float bz,
                                          float (*cv)[16], int (*ci)[16],
                                          float (*cx)[16], float (*cy)[16], float (*cz)[16],
                                          float* ws, float* out, int cloud,
                                          float& s0, float& s1, float& s2){
  float v = bv; int i = bi;
  #pragma unroll
  for (int m=1;m<64;m<<=1){
    float v2=__shfl_xor(v,m,64); int i2=__shfl_xor(i,m,64);
    if (v2 > v || (v2 == v && i2 < i)){ v=v2; i=i2; }
  }
  const int p = r & 1;
  if ((i >> 4) == t){ cv[p][wv]=v; ci[p][wv]=i; cx[p][wv]=bx; cy[p][wv]=by; cz[p][wv]=bz; }
  __syncthreads();
  float wvv = cv[p][0]; int wi = ci[p][0]; int slot = 0;
  #pragma unroll
  for (int e=1;e<16;e++){
    float v2=cv[p][e]; int i2=ci[p][e];
    if (v2 > wvv || (v2 == wvv && i2 < wi)){ wvv=v2; wi=i2; slot=e; }
  }
  s0 = cx[p][slot]; s1 = cy[p][slot]; s2 = cz[p][slot];
  if (t == 0){
    float* sw = ws + WS_SEL + cloud*48 + r*3;
    sw[0]=s0; sw[1]=s1; sw[2]=s2;
    size_t o = (cloud<B_) ? (size_t)(OUT_SRCKP + cloud*48 + r*3)
                          : (size_t)(OUT_TGTKP + (cloud-B_)*48 + r*3);
    out[o]=s0; out[o+1]=s1; out[o+2]=s2;
  }
}

__global__ __launch_bounds__(1024, 4) void fps_kernel(const float* __restrict__ src,
                                                      const float* __restrict__ tgt,
                                                      const float* __restrict__ kw1,
                                                      const float* __restrict__ kb1,
                                                      const float* __restrict__ kw2,
                                                      const float* __restrict__ kb2,
                                                      float* ws, float* out){
  const int cloud = blockIdx.x; const int t = threadIdx.x;
  const int wv = t >> 6;
  const int lane = t & 63;
  const float* base = (cloud < B_) ? (src + (size_t)cloud*N_*3)
                                   : (tgt + (size_t)cloud*N_*3 - (size_t)B_*N_*3);
  __shared__ alignas(16) float kpl[48];
  __shared__ alignas(16) float h[128];
  __shared__ float cv[2][16]; __shared__ int ci[2][16];
  __shared__ float cx[2][16]; __shared__ float cy[2][16]; __shared__ float cz[2][16];
  __shared__ float red[96];

  // issue the 12 point float4 loads NOW; consume after kp-MLP (latency hidden)
  float4 raw[12];
  {
    const float4* b4 = (const float4*)(base + (size_t)t*48);
    #pragma unroll
    for (int q=0;q<12;q++) raw[q] = b4[q];
  }

  // kp-MLP layer1 (order-identical; float4-batched loads)
  const float* lat = ws + WS_LAT + cloud*128;
  if (t < 128){
    float acc = kb1[t];
    const float4* w4 = (const float4*)(kw1 + t*128);
    const float4* l4 = (const float4*)lat;
    #pragma unroll 8
    for (int c4=0;c4<32;c4++){
      float4 wq=w4[c4], lq=l4[c4];
      acc = fmaf(lq.x, wq.x, acc);
      acc = fmaf(lq.y, wq.y, acc);
      acc = fmaf(lq.z, wq.z, acc);
      acc = fmaf(lq.w, wq.w, acc);
    }
    h[t] = fmaxf(acc, 0.0f);
  }
  __syncthreads();
  if (t < 48){
    float acc = kb2[t];
    const float4* w4 = (const float4*)(kw2 + t*128);
    #pragma unroll 8
    for (int c4=0;c4<32;c4++){
      float4 wq=w4[c4];
      float4 hq=*(const float4*)&h[c4*4];
      acc = fmaf(hq.x, wq.x, acc);
      acc = fmaf(hq.y, wq.y, acc);
      acc = fmaf(hq.z, wq.z, acc);
      acc = fmaf(hq.w, wq.w, acc);
    }
    kpl[t] = acc;
  }

  // unpack points (raw loads have had the whole MLP to land)
  float px[16], py[16], pz[16];
  #pragma unroll
  for (int q=0;q<4;q++){
    float4 va=raw[q*3], vb=raw[q*3+1], vc=raw[q*3+2];
    px[q*4  ]=va.x; py[q*4  ]=va.y; pz[q*4  ]=va.z;
    px[q*4+1]=va.w; py[q*4+1]=vb.x; pz[q*4+1]=vb.y;
    px[q*4+2]=vb.z; py[q*4+2]=vb.w; pz[q*4+2]=vc.x;
    px[q*4+3]=vc.y; py[q*4+3]=vc.z; pz[q*4+3]=vc.w;
  }

  // src cloud min/max (exact: fmin/fmax order-independent)
  if (cloud < B_){
    float mn0=3.4e38f,mn1=3.4e38f,mn2=3.4e38f, mx0=-3.4e38f,mx1=-3.4e38f,mx2=-3.4e38f;
    #pragma unroll
    for (int k=0;k<16;k++){
      mn0=fminf(mn0,px[k]); mn1=fminf(mn1,py[k]); mn2=fminf(mn2,pz[k]);
      mx0=fmaxf(mx0,px[k]); mx1=fmaxf(mx1,py[k]); mx2=fmaxf(mx2,pz[k]);
    }
    #pragma unroll
    for (int m=1;m<64;m<<=1){
      mn0=fminf(mn0,__shfl_xor(mn0,m,64)); mx0=fmaxf(mx0,__shfl_xor(mx0,m,64));
      mn1=fminf(mn1,__shfl_xor(mn1,m,64)); mx1=fmaxf(mx1,__shfl_xor(mx1,m,64));
      mn2=fminf(mn2,__shfl_xor(mn2,m,64)); mx2=fmaxf(mx2,__shfl_xor(mx2,m,64));
    }
    if (lane==0){
      red[wv*6+0]=mn0; red[wv*6+1]=mn1; red[wv*6+2]=mn2;
      red[wv*6+3]=mx0; red[wv*6+4]=mx1; red[wv*6+5]=mx2;
    }
    __syncthreads();
    if (t < 6){
      float v = red[t];
      for (int e=1;e<16;e++){
        float v2 = red[e*6+t];
        v = (t<3) ? fminf(v,v2) : fmaxf(v,v2);
      }
      if (t<3) ws[WS_PMIN + cloud*3 + t] = v;
      else     ws[WS_PMAX + cloud*3 + (t-3)] = v;
    }
  }
  __syncthreads();   // kpl ready for all; red/minmax done

  // dmin over 16 keypoints, j-outer
  float mind[16];
  #pragma unroll
  for (int k=0;k<16;k++) mind[k] = 3.4028235e38f;
  for (int j=0;j<K_;j++){
    const float sx=kpl[j*3], sy=kpl[j*3+1], sz=kpl[j*3+2];
    #pragma unroll
    for (int k=0;k<16;k++)
      mind[k] = fminf(mind[k], dist2rn(px[k],py[k],pz[k], sx,sy,sz));
  }

  // round 0: argmax of keypoint-dmin
  float bv = -1.0f; int bi = 0; float bx=0.f, by=0.f, bz=0.f;
  #pragma unroll
  for (int k=0;k<16;k++){
    if (mind[k] > bv){ bv=mind[k]; bi=t*16+k; bx=px[k]; by=py[k]; bz=pz[k]; }
  }
  float s0, s1, s2;
  fps_round(0, t, wv, bv, bi, bx, by, bz, cv, ci, cx, cy, cz, ws, out, cloud, s0, s1, s2);

  // round 1: REPLACE (matches reference)
  bv = -1.0f; bi = 0;
  #pragma unroll
  for (int k=0;k<16;k++){
    float d = dist2rn(px[k],py[k],pz[k], s0,s1,s2);
    mind[k] = d;
    if (d > bv){ bv=d; bi=t*16+k; bx=px[k]; by=py[k]; bz=pz[k]; }
  }
  fps_round(1, t, wv, bv, bi, bx, by, bz, cv, ci, cx, cy, cz, ws, out, cloud, s0, s1, s2);

  // rounds 2..15
  for (int r=2; r<K_; ++r){
    bv = -1.0f; bi = 0;
    #pragma unroll
    for (int k=0;k<16;k++){
      float d = dist2rn(px[k],py[k],pz[k], s0,s1,s2);
      float m = fminf(mind[k], d);
      mind[k] = m;
      if (m > bv){ bv=m; bi=t*16+k; bx=px[k]; by=py[k]; bz=pz[k]; }
    }
    fps_round(r, t, wv, bv, bi, bx, by, bz, cv, ci, cx, cy, cz, ws, out, cloud, s0, s1, s2);
  }
}

// ---------------- cage MLP (redundant per block) + trilinear deform -----------
// v2: float4-batched loads in both MLP chains (FMA order unchanged).
__global__ __launch_bounds__(256) void deform_kernel(const float* __restrict__ src,
                                                     const float* __restrict__ cw1,
                                                     const float* __restrict__ cb1,
                                                     const float* __restrict__ cw2,
                                                     const float* __restrict__ cb2,
                                                     const float* __restrict__ ws,
                                                     float* __restrict__ out){
  const int b = blockIdx.y;
  const int t = threadIdx.x;
  __shared__ float cf[1536];
  __shared__ alignas(16) float diff[48];
  __shared__ alignas(16) float hh[128];

  if (t<48) diff[t] = __fsub_rn(ws[WS_SEL + (B_+b)*48 + t], ws[WS_SEL + b*48 + t]);
  __syncthreads();
  if (t<128){
    const float4* w4 = (const float4*)(cw1 + t*48);
    float acc = cb1[t];
    #pragma unroll
    for (int j4=0;j4<12;j4++){
      float4 wq=w4[j4];
      float4 dq=*(const float4*)&diff[j4*4];
      acc = fmaf(dq.x, wq.x, acc);
      acc = fmaf(dq.y, wq.y, acc);
      acc = fmaf(dq.z, wq.z, acc);
      acc = fmaf(dq.w, wq.w, acc);
    }
    hh[t] = fmaxf(acc, 0.0f);
  }
  __syncthreads();
  for (int o = t; o < 1536; o += 256){
    const float4* w4 = (const float4*)(cw2 + o*128);
    float acc = cb2[o];
    #pragma unroll 8
    for (int c4=0;c4<32;c4++){
      float4 wq=w4[c4];
      float4 hq=*(const float4*)&hh[c4*4];
      acc = fmaf(hq.x, wq.x, acc);
      acc = fmaf(hq.y, wq.y, acc);
      acc = fmaf(hq.z, wq.z, acc);
      acc = fmaf(hq.w, wq.w, acc);
    }
    int flat = o/3, coord = o - flat*3;
    int u = flat>>6, v=(flat>>3)&7, z=flat&7;
    int g = (coord==0)?u:((coord==1)?v:z);
    float gv = (g==7)?1.0f:(float)g*(1.0f/7.0f);
    cf[o] = gv + acc;
  }
  __syncthreads();

  const float mn0 = ws[WS_PMIN+b*3+0], mn1 = ws[WS_PMIN+b*3+1], mn2 = ws[WS_PMIN+b*3+2];
  const float mx0 = ws[WS_PMAX+b*3+0], mx1 = ws[WS_PMAX+b*3+1], mx2 = ws[WS_PMAX+b*3+2];

  #pragma unroll
  for (int k=0;k<4;k++){
    const int n = blockIdx.x*1024 + k*256 + t;
    const float* p = src + ((size_t)b*N_ + n)*3;
    float pt[3]; int id[3]; float w[3];
    #pragma unroll
    for (int c=0;c<3;c++){
      float pv = p[c];
      float mnv = (c==0)?mn0:((c==1)?mn1:mn2);
      float mxv = (c==0)?mx0:((c==1)?mx1:mx2);
      float denom = __fadd_rn(__fsub_rn(mxv, mnv), 1e-6f);
      float tc = __fmul_rn(__fdiv_rn(__fsub_rn(pv, mnv), denom), 7.0f);
      int ic = (int)tc; ic = min(max(ic,0),6);
      pt[c]=pv; id[c]=ic; w[c]=__fsub_rn(tc, (float)ic);
    }
    const int flat = (id[0]<<6) + (id[1]<<3) + id[2];
    const float* c000 = cf + flat*3;
    const float wx=w[0], wy=w[1], wz=w[2];
    const float ux=__fsub_rn(1.0f,wx), uy=__fsub_rn(1.0f,wy), uz=__fsub_rn(1.0f,wz);
    const float w000=__fmul_rn(__fmul_rn(ux,uy),uz);
    const float w100=__fmul_rn(__fmul_rn(wx,uy),uz);
    const float w010=__fmul_rn(__fmul_rn(ux,wy),uz);
    const float w110=__fmul_rn(__fmul_rn(wx,wy),uz);
    const float w001=__fmul_rn(__fmul_rn(ux,uy),wz);
    const float w101=__fmul_rn(__fmul_rn(wx,uy),wz);
    const float w011=__fmul_rn(__fmul_rn(ux,wy),wz);
    const float w111=__fmul_rn(__fmul_rn(wx,wy),wz);
    #pragma unroll
    for (int c=0;c<3;c++){
      float d = __fmul_rn(w000, c000[c]);
      d = __fadd_rn(d, __fmul_rn(w100, c000[192+c]));
      d = __fadd_rn(d, __fmul_rn(w010, c000[24+c]));
      d = __fadd_rn(d, __fmul_rn(w110, c000[216+c]));
      d = __fadd_rn(d, __fmul_rn(w001, c000[3+c]));
      d = __fadd_rn(d, __fmul_rn(w101, c000[195+c]));
      d = __fadd_rn(d, __fmul_rn(w011, c000[27+c]));
      d = __fadd_rn(d, __fmul_rn(w111, c000[219+c]));
      out[((size_t)b*N_+n)*3 + c] = __fadd_rn(pt[c], d);
    }
  }
}

// ---------------- launch ------------------------------------------------------
extern "C" void kernel_launch(void* const* d_in, const int* in_sizes, int n_in,
                              void* d_out, int out_size, void* d_ws, size_t ws_size,
                              hipStream_t stream){
  const float* src = (const float*)d_in[0];
  const float* tgt = (const float*)d_in[1];
  float* ws = (float*)d_ws;
  float* out = (float*)d_out;

  EncW ew;
  ew.w1 =(const float*)d_in[2];  ew.b1 =(const float*)d_in[3];
  ew.g1 =(const float*)d_in[4];  ew.be1=(const float*)d_in[5];
  ew.m1 =(const float*)d_in[6];  ew.v1 =(const float*)d_in[7];
  ew.w2 =(const float*)d_in[8];  ew.b2 =(const float*)d_in[9];
  ew.g2 =(const float*)d_in[10]; ew.be2=(const float*)d_in[11];
  ew.m2 =(const float*)d_in[12]; ew.v2 =(const float*)d_in[13];
  ew.w3 =(const float*)d_in[14]; ew.b3 =(const float*)d_in[15];
  ew.g3 =(const float*)d_in[16]; ew.be3=(const float*)d_in[17];
  ew.m3 =(const float*)d_in[18]; ew.v3 =(const float*)d_in[19];

  prep_kernel<<<128, 256, 0, stream>>>(ew, ws);
  encode_kernel<<<dim3(256,32), 256, 0, stream>>>(src, tgt, ws, ws + WS_LAT);
  fps_kernel<<<32, 1024, 0, stream>>>(src, tgt,
      (const float*)d_in[20], (const float*)d_in[21],
      (const float*)d_in[22], (const float*)d_in[23], ws, out);
  deform_kernel<<<dim3(16,16), 256, 0, stream>>>(src,
      (const float*)d_in[24], (const float*)d_in[25],
      (const float*)d_in[26], (const float*)d_in[27], ws, out);
}